// Round 10
// baseline (336.256 us; speedup 1.0000x reference)
//
#include <hip/hip_runtime.h>
#include <hip/hip_cooperative_groups.h>

namespace cg = cooperative_groups;

// Problem constants
#define NB 2
#define NL 256
#define ND 512
#define NH 8
#define NR 64
#define NS 9
#define NF 576
#define NHS 72      // NH*NS
#define WQROW 4608  // NR*NHS
#define RWIN 12     // rbf window: terms beyond 5.5*delta < 2e-7 -> negligible

typedef __attribute__((ext_vector_type(8))) short bf16x8;
typedef __attribute__((ext_vector_type(4))) float f32x4;

__device__ __forceinline__ ushort f2b(float f) {   // fp32 -> bf16 RNE
    union { float f; unsigned u; } c; c.f = f;
    unsigned u = c.u;
    return (ushort)((u + 0x7FFF + ((u >> 16) & 1)) >> 16);
}

__device__ __forceinline__ float block_sum8(float v, float* s_red) {
    #pragma unroll
    for (int off = 32; off; off >>= 1) v += __shfl_xor(v, off, 64);
    __syncthreads();
    if ((threadIdx.x & 63) == 0) s_red[threadIdx.x >> 6] = v;
    __syncthreads();
    return ((s_red[0] + s_red[1]) + (s_red[2] + s_red[3])) +
           ((s_red[4] + s_red[5]) + (s_red[6] + s_red[7]));
}

__device__ __forceinline__ float block_sum4(float v, float* s_red) {
    #pragma unroll
    for (int off = 32; off; off >>= 1) v += __shfl_xor(v, off, 64);
    __syncthreads();
    if ((threadIdx.x & 63) == 0) s_red[threadIdx.x >> 6] = v;
    __syncthreads();
    return s_red[0] + s_red[1] + s_red[2] + s_red[3];
}

// ===========================================================================
// MEGA: one cooperative kernel, 512 blocks x 512 threads (2 blocks/CU).
// Phases: A(t2b,k1,k_qk) -> B(attn fused) -> C(ffn1) -> D(ffn2) -> E(ln2)
// ===========================================================================
__global__ __launch_bounds__(512, 4) void mega(
        const float* __restrict__ src, const float* __restrict__ rel_diss,
        const float* __restrict__ rel_dirs, const float* __restrict__ rp_w,
        const float* __restrict__ w1, const float* __restrict__ b1,
        const float* __restrict__ w2, const float* __restrict__ b2,
        const float* __restrict__ g1, const float* __restrict__ be1,
        const float* __restrict__ g2, const float* __restrict__ be2,
        float* __restrict__ Wq, float* __restrict__ sbuf,
        ushort* __restrict__ w1t, ushort* __restrict__ w2t,
        float* __restrict__ x1buf, ushort* __restrict__ x1bf,
        ushort* __restrict__ hbf, float* __restrict__ zpart,
        float* __restrict__ out) {
    cg::grid_group grid = cg::this_grid();
    __shared__ __align__(16) char raw[27712];
    int bid = blockIdx.x;
    int t = threadIdx.x;

    // ---------------- Phase A1: weight transpose + bf16 ----------------
    {
        const float* inp; ushort* outp; int K, N, bx, by;
        if (bid < 256) { inp = w1; outp = w1t; K = 512; N = 2048; bx = bid & 31; by = bid >> 5; }
        else { int id = bid - 256; inp = w2; outp = w2t; K = 2048; N = 512; bx = id & 7; by = id >> 3; }
        float (*tile)[68] = (float(*)[68])raw;   // 64x68x4 = 17408 B
        int n0 = bx * 64, k0 = by * 64;
        {
            int r = t >> 3, cs = (t & 7) * 8;
            const float* ip = inp + (size_t)(k0 + r) * N + n0 + cs;
            *(float4*)&tile[r][cs] = *(const float4*)ip;
            *(float4*)&tile[r][cs + 4] = *(const float4*)(ip + 4);
        }
        __syncthreads();
        {
            int rr = t >> 3, cq = (t & 7) * 8;
            ushort buf[8];
            #pragma unroll
            for (int j = 0; j < 8; ++j) buf[j] = f2b(tile[cq + j][rr]);
            *(uint4*)(outp + (size_t)(n0 + rr) * K + k0 + cq) = *(uint4*)buf;
        }
    }
    __syncthreads();

    // ---------------- Phase A2: k1 (Wq) ----------------
    {
        int rt = bid & 63, h = bid >> 6;
        float (*s_src)[64] = (float(*)[64])raw;          // 2048 B
        float* s_B = (float*)(raw + 2048);               // 16384 B
        int r0 = rt * 8;
        s_src[t >> 6][t & 63] = src[(size_t)(r0 + (t >> 6)) * ND + h * 64 + (t & 63)];
        int ff = t & 63, g = t >> 6;
        int lr = t >> 3, lq = t & 7;
        const float* bsrc = rp_w + h * 64;
        #pragma unroll 1
        for (int s = 0; s < NS; ++s) {
            __syncthreads();
            #pragma unroll
            for (int i = 0; i < 2; ++i) {
                int slot = i * 8 + lq;
                float4 v = *(const float4*)(bsrc + (size_t)(s * 64 + lr) * ND + slot * 4);
                int sw = slot ^ (lr & 7);
                *(float4*)&s_B[lr * 64 + sw * 4] = v;
            }
            __syncthreads();
            float a0 = 0.f;
            #pragma unroll
            for (int d4 = 0; d4 < 16; ++d4) {
                int sw = d4 ^ (ff & 7);
                float4 bv = *(const float4*)&s_B[ff * 64 + sw * 4];
                float4 s0 = *(const float4*)&s_src[g][d4 * 4];
                a0 = fmaf(bv.x, s0.x, a0);
                a0 = fmaf(bv.y, s0.y, a0);
                a0 = fmaf(bv.z, s0.z, a0);
                a0 = fmaf(bv.w, s0.w, a0);
            }
            Wq[(size_t)(r0 + g) * WQROW + ff * NHS + h * NS + s] = a0;
        }
    }
    __syncthreads();

    // ---------------- Phase A3: k_qk (base logits) ----------------
    {
        int mt = bid & 3, lt = (bid >> 2) & 7, bh = bid >> 5;
        int b = bh >> 3, h = bh & 7;
        int m0 = mt * 64, l0 = lt * 32;
        float (*s_A)[68] = (float(*)[68])raw;             // 8704 B
        float (*s_Bq)[68] = (float(*)[68])(raw + 8704);   // 17408 B
        {
            int row = t >> 4, c4 = t & 15;
            float4 v = *(const float4*)(src + (size_t)(b * NL + l0 + row) * ND + h * 64 + c4 * 4);
            *(float4*)&s_A[row][c4 * 4] = v;
        }
        {
            int mr = t >> 3, q8 = t & 7;
            const float* kp = src + (size_t)(b * NL + m0 + mr) * ND + h * 64 + q8 * 8;
            float4 v0 = *(const float4*)kp;
            float4 v1 = *(const float4*)(kp + 4);
            int d = q8 * 8;
            s_Bq[d + 0][mr] = v0.x; s_Bq[d + 1][mr] = v0.y;
            s_Bq[d + 2][mr] = v0.z; s_Bq[d + 3][mr] = v0.w;
            s_Bq[d + 4][mr] = v1.x; s_Bq[d + 5][mr] = v1.y;
            s_Bq[d + 6][mr] = v1.z; s_Bq[d + 7][mr] = v1.w;
        }
        __syncthreads();
        int tx = t & 15, ty = t >> 4;   // ty 0..31
        float acc[4] = {};
        #pragma unroll
        for (int d = 0; d < 64; ++d) {
            float a0 = s_A[ty][d];
            float4 bv = *(const float4*)&s_Bq[d][tx * 4];
            acc[0] = fmaf(a0, bv.x, acc[0]);
            acc[1] = fmaf(a0, bv.y, acc[1]);
            acc[2] = fmaf(a0, bv.z, acc[2]);
            acc[3] = fmaf(a0, bv.w, acc[3]);
        }
        size_t off = ((size_t)bh * NL + l0 + ty) * NL + m0 + tx * 4;
        *(float4*)(sbuf + off) = make_float4(acc[0] * 0.125f, acc[1] * 0.125f,
                                             acc[2] * 0.125f, acc[3] * 0.125f);
    }
    grid.sync();

    // ---------------- Phase B: attention fused (row = bid) ----------------
    {
        int row = bid;
        int b = row >> 8;
        int l = row & 255;
        int m = t & 255;
        int hg = t >> 8;
        float (*s_wq)[76] = (float(*)[76])raw;           // 19456 B
        float (*s_l)[NL] = (float(*)[NL])(raw + 19456);  // 8192 B
        float* s_red = (float*)(raw + 27648);            // 32 B

        const float* wrow = Wq + (size_t)row * WQROW;
        #pragma unroll
        for (int i = 0; i < 9; ++i) {
            int flat = i * 512 + t;
            int r = flat / 72, c = flat - 72 * r;
            s_wq[r][c] = wrow[flat];
        }

        float dist = rel_diss[(size_t)row * NL + m];
        const float* dirp = rel_dirs + ((size_t)row * NL + m) * 3;
        float x = dirp[0], y = dirp[1], z = dirp[2];
        float tcl = fminf(fmaxf(dist * 0.1f, 0.f), 1.f);
        float env = 0.5f * (__cosf(3.14159265358979f * tcl) + 1.f);
        int rc = (int)floorf(dist * 6.3f + 0.5f);
        int rlo = min(max(rc - 6, 0), NR - RWIN);
        float sph[NS];
        sph[0] = 0.28209479177387814f * env;
        sph[1] = 0.4886025119029199f * y * env;
        sph[2] = 0.4886025119029199f * z * env;
        sph[3] = 0.4886025119029199f * x * env;
        sph[4] = 1.0925484305920792f * x * y * env;
        sph[5] = 1.0925484305920792f * y * z * env;
        sph[6] = 0.31539156525252005f * (3.f * z * z - 1.f) * env;
        sph[7] = 1.0925484305920792f * x * z * env;
        sph[8] = 0.5462742152960396f * (x * x - y * y) * env;

        __syncthreads();

        float acc[36];
        #pragma unroll
        for (int i = 0; i < 36; ++i) acc[i] = 0.f;
        #pragma unroll 4
        for (int rw = 0; rw < RWIN; ++rw) {
            int r = rlo + rw;
            float df = dist - r * (10.f / 63.f);
            float rbf = __expf(-df * df * 20.48f);
            const float* wp = &s_wq[r][hg * 36];
            #pragma unroll
            for (int q = 0; q < 9; ++q) {
                float4 w = *(const float4*)(wp + q * 4);
                acc[q * 4 + 0] = fmaf(w.x, rbf, acc[q * 4 + 0]);
                acc[q * 4 + 1] = fmaf(w.y, rbf, acc[q * 4 + 1]);
                acc[q * 4 + 2] = fmaf(w.z, rbf, acc[q * 4 + 2]);
                acc[q * 4 + 3] = fmaf(w.w, rbf, acc[q * 4 + 3]);
            }
        }

        const float* sb = sbuf + (((size_t)(b * NH + hg * 4) * NL) + l) * NL + m;
        #pragma unroll
        for (int hh = 0; hh < 4; ++hh) {
            float sc = 0.f;
            #pragma unroll
            for (int s = 0; s < NS; ++s) sc = fmaf(sph[s], acc[hh * NS + s], sc);
            s_l[hg * 4 + hh][m] = sc + sb[(size_t)hh * NL * NL];
        }
        __syncthreads();

        int wv = t >> 6, lane = t & 63;
        {
            float v0 = s_l[wv][lane], v1 = s_l[wv][lane + 64];
            float v2 = s_l[wv][lane + 128], v3 = s_l[wv][lane + 192];
            float mx = fmaxf(fmaxf(v0, v1), fmaxf(v2, v3));
            #pragma unroll
            for (int off = 32; off; off >>= 1) mx = fmaxf(mx, __shfl_xor(mx, off, 64));
            float p0 = __expf(v0 - mx), p1 = __expf(v1 - mx);
            float p2 = __expf(v2 - mx), p3 = __expf(v3 - mx);
            float sm = p0 + p1 + p2 + p3;
            #pragma unroll
            for (int off = 32; off; off >>= 1) sm += __shfl_xor(sm, off, 64);
            float inv = 1.f / sm;
            s_l[wv][lane] = p0 * inv;
            s_l[wv][lane + 64] = p1 * inv;
            s_l[wv][lane + 128] = p2 * inv;
            s_l[wv][lane + 192] = p3 * inv;
        }
        __syncthreads();

        int d = t;
        int h0 = t >> 6;
        float a0 = 0.f, a1 = 0.f, a2 = 0.f, a3 = 0.f;
        const float* vbase = src + (size_t)b * NL * ND + d;
        #pragma unroll 2
        for (int mm = 0; mm < NL; mm += 4) {
            float4 wv4 = *(const float4*)&s_l[h0][mm];
            a0 = fmaf(wv4.x, vbase[(size_t)(mm + 0) * ND], a0);
            a1 = fmaf(wv4.y, vbase[(size_t)(mm + 1) * ND], a1);
            a2 = fmaf(wv4.z, vbase[(size_t)(mm + 2) * ND], a2);
            a3 = fmaf(wv4.w, vbase[(size_t)(mm + 3) * ND], a3);
        }
        float av = (a0 + a1) + (a2 + a3);

        float x0 = src[(size_t)row * ND + d] + av;
        float mu = block_sum8(x0, s_red) * (1.f / 512.f);
        float e0 = x0 - mu;
        float var = block_sum8(e0 * e0, s_red) * (1.f / 512.f);
        float rs = rsqrtf(var + 1e-5f);
        float o = e0 * rs * g1[d] + be1[d];
        x1buf[(size_t)row * ND + d] = o;
        x1bf[(size_t)row * ND + d] = f2b(o);
    }
    grid.sync();

    // ---------------- Phase C: ffn1 MFMA (64m x 32n tiles) ----------------
    {
        const int K = 512, N = 2048;
        ushort (*As)[40] = (ushort(*)[40])raw;            // 5120 B
        ushort (*Bs)[40] = (ushort(*)[40])(raw + 5120);   // 2560 B
        int n0 = (bid & 63) * 32;
        int m0 = (bid >> 6) * 64;
        int w = t >> 6, l = t & 63;
        int lr = l & 15, lk = (l >> 4) * 8;
        int sr = t >> 3, sq = (t & 7) * 4;
        f32x4 acc = {0.f, 0.f, 0.f, 0.f};
        const ushort* Ap = x1bf + (size_t)(m0 + sr) * K + sq;
        const ushort* Bp = w1t + (size_t)(n0 + sr) * K + sq;   // valid for t<256
        for (int k0 = 0; k0 < K; k0 += 32) {
            uint2 av = *(const uint2*)(Ap + k0);
            uint2 bv = {0, 0};
            if (t < 256) bv = *(const uint2*)(Bp + k0);
            __syncthreads();
            *(uint2*)&As[sr][sq] = av;
            if (t < 256) *(uint2*)&Bs[sr][sq] = bv;
            __syncthreads();
            bf16x8 af = *(const bf16x8*)&As[(w & 3) * 16 + lr][lk];
            bf16x8 bf = *(const bf16x8*)&Bs[(w >> 2) * 16 + lr][lk];
            acc = __builtin_amdgcn_mfma_f32_16x16x32_bf16(af, bf, acc, 0, 0, 0);
        }
        int rbase = m0 + (w & 3) * 16 + (l >> 4) * 4;
        int col = n0 + (w >> 2) * 16 + lr;
        float bb = b1[col];
        #pragma unroll
        for (int e = 0; e < 4; ++e) {
            float v = acc[e] + bb;
            hbf[(size_t)(rbase + e) * N + col] = f2b(v >= 0.f ? v : 0.01f * v);
        }
    }
    grid.sync();

    // ---------------- Phase D: ffn2 MFMA split-K (64m x 32n x 4ks) --------
    {
        const int K = 2048, N = 512;
        ushort (*As)[40] = (ushort(*)[40])raw;
        ushort (*Bs)[40] = (ushort(*)[40])(raw + 5120);
        int n0 = (bid & 15) * 32;
        int m0 = ((bid >> 4) & 7) * 64;
        int ks = bid >> 7;
        int w = t >> 6, l = t & 63;
        int lr = l & 15, lk = (l >> 4) * 8;
        int sr = t >> 3, sq = (t & 7) * 4;
        f32x4 acc = {0.f, 0.f, 0.f, 0.f};
        const ushort* Ap = hbf + (size_t)(m0 + sr) * K + ks * 512 + sq;
        const ushort* Bp = w2t + (size_t)(n0 + sr) * K + ks * 512 + sq;  // t<256
        for (int k0 = 0; k0 < 512; k0 += 32) {
            uint2 av = *(const uint2*)(Ap + k0);
            uint2 bv = {0, 0};
            if (t < 256) bv = *(const uint2*)(Bp + k0);
            __syncthreads();
            *(uint2*)&As[sr][sq] = av;
            if (t < 256) *(uint2*)&Bs[sr][sq] = bv;
            __syncthreads();
            bf16x8 af = *(const bf16x8*)&As[(w & 3) * 16 + lr][lk];
            bf16x8 bf = *(const bf16x8*)&Bs[(w >> 2) * 16 + lr][lk];
            acc = __builtin_amdgcn_mfma_f32_16x16x32_bf16(af, bf, acc, 0, 0, 0);
        }
        float* op = zpart + ((size_t)ks << 18);
        int rbase = m0 + (w & 3) * 16 + (l >> 4) * 4;
        int col = n0 + (w >> 2) * 16 + lr;
        #pragma unroll
        for (int e = 0; e < 4; ++e) op[(size_t)(rbase + e) * N + col] = acc[e];
    }
    grid.sync();

    // ---------------- Phase E: final LN ----------------
    {
        float* s_red = (float*)raw;
        int row = bid, d = t;
        size_t off = (size_t)row * ND + d;
        float z = x1buf[off] + b2[d];
        #pragma unroll
        for (int ks = 0; ks < 4; ++ks) z += zpart[((size_t)ks << 18) + off];
        float mu = block_sum8(z, s_red) * (1.f / 512.f);
        float e0 = z - mu;
        float var = block_sum8(e0 * e0, s_red) * (1.f / 512.f);
        float rs = rsqrtf(var + 1e-5f);
        out[off] = e0 * rs * g2[d] + be2[d];
    }
}

// ===========================================================================
// FALLBACK: round-9 5-kernel path (used only if cooperative launch fails)
// ===========================================================================
__global__ __launch_bounds__(256, 4) void k_pre(const float* __restrict__ src,
                                                const float* __restrict__ rp_w,
                                                const float* __restrict__ w1,
                                                const float* __restrict__ w2,
                                                float* __restrict__ Wq,
                                                float* __restrict__ sbuf,
                                                ushort* __restrict__ w1t,
                                                ushort* __restrict__ w2t) {
    __shared__ __align__(16) char raw[26368];
    int bi = blockIdx.x;
    int t = threadIdx.x;
    if (bi < 512) {
        const float* in; ushort* out; int K, N, bx, by;
        if (bi < 256) { in = w1; out = w1t; K = 512; N = 2048; bx = bi & 31; by = bi >> 5; }
        else { int id = bi - 256; in = w2; out = w2t; K = 2048; N = 512; bx = id & 7; by = id >> 3; }
        float (*tile)[65] = (float(*)[65])raw;
        int n0 = bx * 64, k0 = by * 64;
        int r = t >> 4, c4 = (t & 15) * 4;
        #pragma unroll
        for (int i = 0; i < 4; ++i) {
            int kk = i * 16 + r;
            float4 v = *(const float4*)(in + (size_t)(k0 + kk) * N + n0 + c4);
            tile[kk][c4 + 0] = v.x;
            tile[kk][c4 + 1] = v.y;
            tile[kk][c4 + 2] = v.z;
            tile[kk][c4 + 3] = v.w;
        }
        __syncthreads();
        int rr = t >> 2, cq = (t & 3) * 16;
        ushort buf[16];
        #pragma unroll
        for (int j = 0; j < 16; ++j) buf[j] = f2b(tile[cq + j][rr]);
        ushort* op = out + (size_t)(n0 + rr) * K + k0 + cq;
        *(uint4*)(op) = *(uint4*)&buf[0];
        *(uint4*)(op + 8) = *(uint4*)&buf[8];
    } else if (bi < 1024) {
        int id = bi - 512;
        int rt = id & 63, h = id >> 6;
        float (*s_src)[64] = (float(*)[64])raw;
        float* s_B = (float*)(raw + 2048);
        int r0 = rt * 8;
        {
            int sr = t >> 5;
            int sc = (t & 31) * 2;
            *(float2*)&s_src[sr][sc] =
                *(const float2*)(src + (size_t)(r0 + sr) * ND + h * 64 + sc);
        }
        int ff = t & 63;
        int g  = t >> 6;
        int lr = t >> 2;
        int lq = t & 3;
        const float* bsrc = rp_w + h * 64;
        #pragma unroll 1
        for (int s = 0; s < NS; ++s) {
            __syncthreads();
            #pragma unroll
            for (int i = 0; i < 4; ++i) {
                int slot = i * 4 + lq;
                float4 v = *(const float4*)(bsrc + (size_t)(s * 64 + lr) * ND + slot * 4);
                int sw = slot ^ (lr & 7);
                *(float4*)&s_B[lr * 64 + sw * 4] = v;
            }
            __syncthreads();
            float a0 = 0.f, a1 = 0.f;
            #pragma unroll
            for (int d4 = 0; d4 < 16; ++d4) {
                int sw = d4 ^ (ff & 7);
                float4 bv = *(const float4*)&s_B[ff * 64 + sw * 4];
                float4 s0 = *(const float4*)&s_src[2 * g][d4 * 4];
                float4 s1 = *(const float4*)&s_src[2 * g + 1][d4 * 4];
                a0 = fmaf(bv.x, s0.x, a0);
                a0 = fmaf(bv.y, s0.y, a0);
                a0 = fmaf(bv.z, s0.z, a0);
                a0 = fmaf(bv.w, s0.w, a0);
                a1 = fmaf(bv.x, s1.x, a1);
                a1 = fmaf(bv.y, s1.y, a1);
                a1 = fmaf(bv.z, s1.z, a1);
                a1 = fmaf(bv.w, s1.w, a1);
            }
            Wq[(size_t)(r0 + 2 * g) * WQROW + ff * NHS + h * NS + s] = a0;
            Wq[(size_t)(r0 + 2 * g + 1) * WQROW + ff * NHS + h * NS + s] = a1;
        }
    } else {
        int id = bi - 1024;
        int mt = id & 3, lt = (id >> 2) & 7, bh = id >> 5;
        int b = bh >> 3, h = bh & 7;
        int m0 = mt * 64, l0 = lt * 32;
        float (*s_A)[68] = (float(*)[68])raw;
        float (*s_B)[68] = (float(*)[68])(raw + 8704);
        #pragma unroll
        for (int i = 0; i < 2; ++i) {
            int idx = i * 256 + t;
            int row = idx >> 4, c4 = idx & 15;
            float4 v = *(const float4*)(src + (size_t)(b * NL + l0 + row) * ND + h * 64 + c4 * 4);
            *(float4*)&s_A[row][c4 * 4] = v;
        }
        {
            int mr = t >> 2, qd = t & 3;
            const float* kp = src + (size_t)(b * NL + m0 + mr) * ND + h * 64 + qd * 16;
            #pragma unroll
            for (int q = 0; q < 4; ++q) {
                float4 v = *(const float4*)(kp + q * 4);
                int d = qd * 16 + q * 4;
                s_B[d + 0][mr] = v.x;
                s_B[d + 1][mr] = v.y;
                s_B[d + 2][mr] = v.z;
                s_B[d + 3][mr] = v.w;
            }
        }
        __syncthreads();
        int tx = t & 15, ty = t >> 4;
        int ty2 = ty * 2;
        float acc[2][4] = {};
        #pragma unroll
        for (int d = 0; d < 64; ++d) {
            float a0 = s_A[ty2][d];
            float a1 = s_A[ty2 + 1][d];
            float4 bv = *(const float4*)&s_B[d][tx * 4];
            acc[0][0] = fmaf(a0, bv.x, acc[0][0]);
            acc[0][1] = fmaf(a0, bv.y, acc[0][1]);
            acc[0][2] = fmaf(a0, bv.z, acc[0][2]);
            acc[0][3] = fmaf(a0, bv.w, acc[0][3]);
            acc[1][0] = fmaf(a1, bv.x, acc[1][0]);
            acc[1][1] = fmaf(a1, bv.y, acc[1][1]);
            acc[1][2] = fmaf(a1, bv.z, acc[1][2]);
            acc[1][3] = fmaf(a1, bv.w, acc[1][3]);
        }
        #pragma unroll
        for (int i = 0; i < 2; ++i) {
            size_t off = ((size_t)bh * NL + l0 + ty2 + i) * NL + m0 + tx * 4;
            *(float4*)(sbuf + off) = make_float4(acc[i][0] * 0.125f, acc[i][1] * 0.125f,
                                                 acc[i][2] * 0.125f, acc[i][3] * 0.125f);
        }
    }
}

__global__ __launch_bounds__(512, 4) void k2_fused(const float* __restrict__ src,
                                                   const float* __restrict__ rel_diss,
                                                   const float* __restrict__ rel_dirs,
                                                   const float* __restrict__ Wq,
                                                   const float* __restrict__ sbuf,
                                                   const float* __restrict__ gamma1,
                                                   const float* __restrict__ beta1,
                                                   float* __restrict__ x1buf,
                                                   ushort* __restrict__ x1bf) {
    int row = blockIdx.x;
    int b = row >> 8;
    int l = row & 255;
    int t = threadIdx.x;
    int m = t & 255;
    int hg = t >> 8;
    __shared__ float s_wq[64][76];
    __shared__ float s_l[NH][NL];
    __shared__ float s_red[8];

    const float* wrow = Wq + (size_t)row * WQROW;
    #pragma unroll
    for (int i = 0; i < 9; ++i) {
        int flat = i * 512 + t;
        int r = flat / 72, c = flat - 72 * r;
        s_wq[r][c] = wrow[flat];
    }
    float dist = rel_diss[(size_t)row * NL + m];
    const float* dirp = rel_dirs + ((size_t)row * NL + m) * 3;
    float x = dirp[0], y = dirp[1], z = dirp[2];
    float tcl = fminf(fmaxf(dist * 0.1f, 0.f), 1.f);
    float env = 0.5f * (__cosf(3.14159265358979f * tcl) + 1.f);
    int rc = (int)floorf(dist * 6.3f + 0.5f);
    int rlo = min(max(rc - 6, 0), NR - RWIN);
    float sph[NS];
    sph[0] = 0.28209479177387814f * env;
    sph[1] = 0.4886025119029199f * y * env;
    sph[2] = 0.4886025119029199f * z * env;
    sph[3] = 0.4886025119029199f * x * env;
    sph[4] = 1.0925484305920792f * x * y * env;
    sph[5] = 1.0925484305920792f * y * z * env;
    sph[6] = 0.31539156525252005f * (3.f * z * z - 1.f) * env;
    sph[7] = 1.0925484305920792f * x * z * env;
    sph[8] = 0.5462742152960396f * (x * x - y * y) * env;
    __syncthreads();
    float acc[36];
    #pragma unroll
    for (int i = 0; i < 36; ++i) acc[i] = 0.f;
    #pragma unroll 4
    for (int rw = 0; rw < RWIN; ++rw) {
        int r = rlo + rw;
        float df = dist - r * (10.f / 63.f);
        float rbf = __expf(-df * df * 20.48f);
        const float* wp = &s_wq[r][hg * 36];
        #pragma unroll
        for (int q = 0; q < 9; ++q) {
            float4 w = *(const float4*)(wp + q * 4);
            acc[q * 4 + 0] = fmaf(w.x, rbf, acc[q * 4 + 0]);
            acc[q * 4 + 1] = fmaf(w.y, rbf, acc[q * 4 + 1]);
            acc[q * 4 + 2] = fmaf(w.z, rbf, acc[q * 4 + 2]);
            acc[q * 4 + 3] = fmaf(w.w, rbf, acc[q * 4 + 3]);
        }
    }
    const float* sb = sbuf + (((size_t)(b * NH + hg * 4) * NL) + l) * NL + m;
    #pragma unroll
    for (int hh = 0; hh < 4; ++hh) {
        float sc = 0.f;
        #pragma unroll
        for (int s = 0; s < NS; ++s) sc = fmaf(sph[s], acc[hh * NS + s], sc);
        s_l[hg * 4 + hh][m] = sc + sb[(size_t)hh * NL * NL];
    }
    __syncthreads();
    int wv = t >> 6, lane = t & 63;
    {
        float v0 = s_l[wv][lane], v1 = s_l[wv][lane + 64];
        float v2 = s_l[wv][lane + 128], v3 = s_l[wv][lane + 192];
        float mx = fmaxf(fmaxf(v0, v1), fmaxf(v2, v3));
        #pragma unroll
        for (int off = 32; off; off >>= 1) mx = fmaxf(mx, __shfl_xor(mx, off, 64));
        float p0 = __expf(v0 - mx), p1 = __expf(v1 - mx);
        float p2 = __expf(v2 - mx), p3 = __expf(v3 - mx);
        float sm = p0 + p1 + p2 + p3;
        #pragma unroll
        for (int off = 32; off; off >>= 1) sm += __shfl_xor(sm, off, 64);
        float inv = 1.f / sm;
        s_l[wv][lane] = p0 * inv;
        s_l[wv][lane + 64] = p1 * inv;
        s_l[wv][lane + 128] = p2 * inv;
        s_l[wv][lane + 192] = p3 * inv;
    }
    __syncthreads();
    int d = t;
    int h0 = t >> 6;
    float a0 = 0.f, a1 = 0.f, a2 = 0.f, a3 = 0.f;
    const float* vbase = src + (size_t)b * NL * ND + d;
    #pragma unroll 2
    for (int mm = 0; mm < NL; mm += 4) {
        float4 wv4 = *(const float4*)&s_l[h0][mm];
        a0 = fmaf(wv4.x, vbase[(size_t)(mm + 0) * ND], a0);
        a1 = fmaf(wv4.y, vbase[(size_t)(mm + 1) * ND], a1);
        a2 = fmaf(wv4.z, vbase[(size_t)(mm + 2) * ND], a2);
        a3 = fmaf(wv4.w, vbase[(size_t)(mm + 3) * ND], a3);
    }
    float av = (a0 + a1) + (a2 + a3);
    float x0 = src[(size_t)row * ND + d] + av;
    float mu = block_sum8(x0, s_red) * (1.f / 512.f);
    float e0 = x0 - mu;
    float var = block_sum8(e0 * e0, s_red) * (1.f / 512.f);
    float rs = rsqrtf(var + 1e-5f);
    float o = e0 * rs * gamma1[d] + beta1[d];
    x1buf[(size_t)row * ND + d] = o;
    x1bf[(size_t)row * ND + d] = f2b(o);
}

__global__ __launch_bounds__(256) void k3_mfma(const ushort* __restrict__ A,
                                               const ushort* __restrict__ Bt,
                                               const float* __restrict__ bias,
                                               ushort* __restrict__ C) {
    const int K = 512, N = 2048;
    int n0 = blockIdx.x * 64, m0 = blockIdx.y * 64;
    int t = threadIdx.x;
    int w = t >> 6, l = t & 63;
    __shared__ ushort As[64][40];
    __shared__ ushort Bs[64][40];
    f32x4 acc0 = {0.f, 0.f, 0.f, 0.f}, acc1 = acc0, acc2 = acc0, acc3 = acc0;
    int sr = t >> 2, sq = (t & 3) * 8;
    const ushort* Ap = A + (size_t)(m0 + sr) * K + sq;
    const ushort* Bp = Bt + (size_t)(n0 + sr) * K + sq;
    int lr = l & 15, lk = (l >> 4) * 8;
    for (int k0 = 0; k0 < K; k0 += 32) {
        uint4 av = *(const uint4*)(Ap + k0);
        uint4 bv = *(const uint4*)(Bp + k0);
        __syncthreads();
        *(uint4*)&As[sr][sq] = av;
        *(uint4*)&Bs[sr][sq] = bv;
        __syncthreads();
        bf16x8 af = *(const bf16x8*)&As[w * 16 + lr][lk];
        bf16x8 b0 = *(const bf16x8*)&Bs[0 * 16 + lr][lk];
        bf16x8 b1v = *(const bf16x8*)&Bs[1 * 16 + lr][lk];
        bf16x8 b2v = *(const bf16x8*)&Bs[2 * 16 + lr][lk];
        bf16x8 b3 = *(const bf16x8*)&Bs[3 * 16 + lr][lk];
        acc0 = __builtin_amdgcn_mfma_f32_16x16x32_bf16(af, b0, acc0, 0, 0, 0);
        acc1 = __builtin_amdgcn_mfma_f32_16x16x32_bf16(af, b1v, acc1, 0, 0, 0);
        acc2 = __builtin_amdgcn_mfma_f32_16x16x32_bf16(af, b2v, acc2, 0, 0, 0);
        acc3 = __builtin_amdgcn_mfma_f32_16x16x32_bf16(af, b3, acc3, 0, 0, 0);
    }
    int rbase = m0 + w * 16 + (l >> 4) * 4;
    #pragma unroll
    for (int e = 0; e < 4; ++e) {
        int row = rbase + e;
        float v;
        int col0 = n0 + lr;
        v = acc0[e] + bias[col0];
        C[(size_t)row * N + col0] = f2b(v >= 0.f ? v : 0.01f * v);
        v = acc1[e] + bias[col0 + 16];
        C[(size_t)row * N + col0 + 16] = f2b(v >= 0.f ? v : 0.01f * v);
        v = acc2[e] + bias[col0 + 32];
        C[(size_t)row * N + col0 + 32] = f2b(v >= 0.f ? v : 0.01f * v);
        v = acc3[e] + bias[col0 + 48];
        C[(size_t)row * N + col0 + 48] = f2b(v >= 0.f ? v : 0.01f * v);
    }
}

__global__ __launch_bounds__(256) void k4_mfma(const ushort* __restrict__ A,
                                               const ushort* __restrict__ Bt,
                                               float* __restrict__ Cp) {
    const int K = 2048, N = 512;
    int n0 = blockIdx.x * 64, m0 = blockIdx.y * 64;
    int ks = blockIdx.z;
    int t = threadIdx.x;
    int w = t >> 6, l = t & 63;
    __shared__ ushort As[64][40];
    __shared__ ushort Bs[64][40];
    f32x4 acc0 = {0.f, 0.f, 0.f, 0.f}, acc1 = acc0, acc2 = acc0, acc3 = acc0;
    int sr = t >> 2, sq = (t & 3) * 8;
    const ushort* Ap = A + (size_t)(m0 + sr) * K + ks * 512 + sq;
    const ushort* Bp = Bt + (size_t)(n0 + sr) * K + ks * 512 + sq;
    int lr = l & 15, lk = (l >> 4) * 8;
    for (int k0 = 0; k0 < 512; k0 += 32) {
        uint4 av = *(const uint4*)(Ap + k0);
        uint4 bv = *(const uint4*)(Bp + k0);
        __syncthreads();
        *(uint4*)&As[sr][sq] = av;
        *(uint4*)&Bs[sr][sq] = bv;
        __syncthreads();
        bf16x8 af = *(const bf16x8*)&As[w * 16 + lr][lk];
        bf16x8 b0 = *(const bf16x8*)&Bs[0 * 16 + lr][lk];
        bf16x8 b1v = *(const bf16x8*)&Bs[1 * 16 + lr][lk];
        bf16x8 b2v = *(const bf16x8*)&Bs[2 * 16 + lr][lk];
        bf16x8 b3 = *(const bf16x8*)&Bs[3 * 16 + lr][lk];
        acc0 = __builtin_amdgcn_mfma_f32_16x16x32_bf16(af, b0, acc0, 0, 0, 0);
        acc1 = __builtin_amdgcn_mfma_f32_16x16x32_bf16(af, b1v, acc1, 0, 0, 0);
        acc2 = __builtin_amdgcn_mfma_f32_16x16x32_bf16(af, b2v, acc2, 0, 0, 0);
        acc3 = __builtin_amdgcn_mfma_f32_16x16x32_bf16(af, b3, acc3, 0, 0, 0);
    }
    float* out = Cp + ((size_t)ks << 18);
    int rbase = m0 + w * 16 + (l >> 4) * 4;
    #pragma unroll
    for (int e = 0; e < 4; ++e) {
        int row = rbase + e;
        int col0 = n0 + lr;
        out[(size_t)row * N + col0] = acc0[e];
        out[(size_t)row * N + col0 + 16] = acc1[e];
        out[(size_t)row * N + col0 + 32] = acc2[e];
        out[(size_t)row * N + col0 + 48] = acc3[e];
    }
}

__global__ __launch_bounds__(256) void k5_final(const float* __restrict__ x1buf,
                                                const float* __restrict__ zpart,
                                                const float* __restrict__ b2,
                                                const float* __restrict__ gamma2,
                                                const float* __restrict__ beta2,
                                                float* __restrict__ out) {
    int row = blockIdx.x;
    int t = threadIdx.x;
    int d0 = t * 2;
    __shared__ float s_red[8];
    size_t off = (size_t)row * ND + d0;
    float2 v = *(const float2*)(x1buf + off);
    float2 bb = *(const float2*)(b2 + d0);
    float z0 = v.x + bb.x, z1 = v.y + bb.y;
    #pragma unroll
    for (int ks = 0; ks < 4; ++ks) {
        float2 p = *(const float2*)(zpart + ((size_t)ks << 18) + off);
        z0 += p.x;
        z1 += p.y;
    }
    float mu = block_sum4(z0 + z1, s_red) * (1.f / 512.f);
    float e0 = z0 - mu, e1 = z1 - mu;
    float var = block_sum4(e0 * e0 + e1 * e1, s_red) * (1.f / 512.f);
    float rs = rsqrtf(var + 1e-5f);
    float2 g = *(const float2*)(gamma2 + d0), be = *(const float2*)(beta2 + d0);
    *(float2*)(out + off) = make_float2(e0 * rs * g.x + be.x, e1 * rs * g.y + be.y);
}

// ---------------------------------------------------------------------------
extern "C" void kernel_launch(void* const* d_in, const int* in_sizes, int n_in,
                              void* d_out, int out_size, void* d_ws, size_t ws_size,
                              hipStream_t stream) {
    const float* src      = (const float*)d_in[0];
    const float* rel_diss = (const float*)d_in[1];
    const float* rel_dirs = (const float*)d_in[2];
    const float* rp_w     = (const float*)d_in[3];
    // d_in[4] = rp_b: constant over softmax axis -> cancels exactly; skipped
    const float* w1  = (const float*)d_in[5];
    const float* b1  = (const float*)d_in[6];
    const float* w2  = (const float*)d_in[7];
    const float* b2  = (const float*)d_in[8];
    const float* g1  = (const float*)d_in[9];
    const float* be1 = (const float*)d_in[10];
    const float* g2  = (const float*)d_in[11];
    const float* be2 = (const float*)d_in[12];
    float* out = (float*)d_out;

    float* ws = (float*)d_ws;
    float* x1buf = ws;                        // 262144 f
    float* sbuf  = x1buf + 262144;            // 1048576 f
    float* zpart = sbuf + 1048576;            // 1048576 f
    float* Wq    = zpart + 1048576;           // 2359296 f
    ushort* w1t  = (ushort*)(Wq + WQROW * 512);   // 1048576 u16
    ushort* w2t  = w1t + 1048576;                 // 1048576 u16
    ushort* x1bf = w2t + 1048576;                 // 262144 u16
    ushort* hbf  = x1bf + 262144;                 // 1048576 u16

    void* args[] = {(void*)&src, (void*)&rel_diss, (void*)&rel_dirs, (void*)&rp_w,
                    (void*)&w1, (void*)&b1, (void*)&w2, (void*)&b2,
                    (void*)&g1, (void*)&be1, (void*)&g2, (void*)&be2,
                    (void*)&Wq, (void*)&sbuf, (void*)&w1t, (void*)&w2t,
                    (void*)&x1buf, (void*)&x1bf, (void*)&hbf, (void*)&zpart,
                    (void*)&out};
    hipError_t err = hipLaunchCooperativeKernel((void*)mega, dim3(512), dim3(512),
                                                args, 0, stream);
    if (err != hipSuccess) {
        (void)hipGetLastError();   // clear sticky error, use fallback path
        k_pre<<<1536, 256, 0, stream>>>(src, rp_w, w1, w2, Wq, sbuf, w1t, w2t);
        k2_fused<<<512, 512, 0, stream>>>(src, rel_diss, rel_dirs, Wq, sbuf,
                                          g1, be1, x1buf, x1bf);
        k3_mfma<<<dim3(32, 8), 256, 0, stream>>>(x1bf, w1t, b1, hbf);
        k4_mfma<<<dim3(8, 8, 4), 256, 0, stream>>>(hbf, w2t, zpart);
        k5_final<<<512, 256, 0, stream>>>(x1buf, zpart, b2, g2, be2, out);
    }
}

// Round 11
// 111.240 us; speedup vs baseline: 3.0228x; 3.0228x over previous
//
#include <hip/hip_runtime.h>

// Problem constants
#define NB 2
#define NL 256
#define ND 512
#define NH 8
#define NR 64
#define NS 9
#define NF 576
#define NHS 72      // NH*NS
#define WQROW 4608  // NR*NHS
#define RWIN 12     // rbf window: terms beyond 5.5*delta < 2e-7 -> negligible

typedef __attribute__((ext_vector_type(8))) short bf16x8;
typedef __attribute__((ext_vector_type(4))) float f32x4;

__device__ __forceinline__ ushort f2b(float f) {   // fp32 -> bf16 RNE
    union { float f; unsigned u; } c; c.f = f;
    unsigned u = c.u;
    return (ushort)((u + 0x7FFF + ((u >> 16) & 1)) >> 16);
}

__device__ __forceinline__ float block_sum8(float v, float* s_red) {
    #pragma unroll
    for (int off = 32; off; off >>= 1) v += __shfl_xor(v, off, 64);
    __syncthreads();
    if ((threadIdx.x & 63) == 0) s_red[threadIdx.x >> 6] = v;
    __syncthreads();
    return ((s_red[0] + s_red[1]) + (s_red[2] + s_red[3])) +
           ((s_red[4] + s_red[5]) + (s_red[6] + s_red[7]));
}

// ---------------------------------------------------------------------------
// K_PRE: union of 4 independent pre-tasks, one dispatch (1536 blocks):
//   [0,256) t2b(w1)  [256,512) t2b(w2)  [512,1024) k1  [1024,1536) k_qk
// Block 0 also zeroes the k4 reduction counters (runs before k4 in stream).
// ---------------------------------------------------------------------------
__global__ __launch_bounds__(256, 4) void k_pre(const float* __restrict__ src,
                                                const float* __restrict__ rp_w,
                                                const float* __restrict__ w1,
                                                const float* __restrict__ w2,
                                                float* __restrict__ Wq,
                                                float* __restrict__ sbuf,
                                                ushort* __restrict__ w1t,
                                                ushort* __restrict__ w2t,
                                                unsigned* __restrict__ ctr) {
    __shared__ __align__(16) char raw[26368];
    int bi = blockIdx.x;
    int t = threadIdx.x;
    if (bi == 0 && t < 8) ctr[t] = 0;

    if (bi < 512) {
        const float* in; ushort* out; int K, N, bx, by;
        if (bi < 256) { in = w1; out = w1t; K = 512; N = 2048; bx = bi & 31; by = bi >> 5; }
        else { int id = bi - 256; in = w2; out = w2t; K = 2048; N = 512; bx = id & 7; by = id >> 3; }
        float (*tile)[65] = (float(*)[65])raw;
        int n0 = bx * 64, k0 = by * 64;
        int r = t >> 4, c4 = (t & 15) * 4;
        #pragma unroll
        for (int i = 0; i < 4; ++i) {
            int kk = i * 16 + r;
            float4 v = *(const float4*)(in + (size_t)(k0 + kk) * N + n0 + c4);
            tile[kk][c4 + 0] = v.x;
            tile[kk][c4 + 1] = v.y;
            tile[kk][c4 + 2] = v.z;
            tile[kk][c4 + 3] = v.w;
        }
        __syncthreads();
        int rr = t >> 2, cq = (t & 3) * 16;
        ushort buf[16];
        #pragma unroll
        for (int j = 0; j < 16; ++j) buf[j] = f2b(tile[cq + j][rr]);
        ushort* op = out + (size_t)(n0 + rr) * K + k0 + cq;
        *(uint4*)(op) = *(uint4*)&buf[0];
        *(uint4*)(op + 8) = *(uint4*)&buf[8];
    } else if (bi < 1024) {
        int id = bi - 512;
        int rt = id & 63, h = id >> 6;
        float (*s_src)[64] = (float(*)[64])raw;
        float* s_B = (float*)(raw + 2048);
        int r0 = rt * 8;
        {
            int sr = t >> 5;
            int sc = (t & 31) * 2;
            *(float2*)&s_src[sr][sc] =
                *(const float2*)(src + (size_t)(r0 + sr) * ND + h * 64 + sc);
        }
        int ff = t & 63;
        int g  = t >> 6;
        int lr = t >> 2;
        int lq = t & 3;
        const float* bsrc = rp_w + h * 64;
        #pragma unroll 1
        for (int s = 0; s < NS; ++s) {
            __syncthreads();
            #pragma unroll
            for (int i = 0; i < 4; ++i) {
                int slot = i * 4 + lq;
                float4 v = *(const float4*)(bsrc + (size_t)(s * 64 + lr) * ND + slot * 4);
                int sw = slot ^ (lr & 7);
                *(float4*)&s_B[lr * 64 + sw * 4] = v;
            }
            __syncthreads();
            float a0 = 0.f, a1 = 0.f;
            #pragma unroll
            for (int d4 = 0; d4 < 16; ++d4) {
                int sw = d4 ^ (ff & 7);
                float4 bv = *(const float4*)&s_B[ff * 64 + sw * 4];
                float4 s0 = *(const float4*)&s_src[2 * g][d4 * 4];
                float4 s1 = *(const float4*)&s_src[2 * g + 1][d4 * 4];
                a0 = fmaf(bv.x, s0.x, a0);
                a0 = fmaf(bv.y, s0.y, a0);
                a0 = fmaf(bv.z, s0.z, a0);
                a0 = fmaf(bv.w, s0.w, a0);
                a1 = fmaf(bv.x, s1.x, a1);
                a1 = fmaf(bv.y, s1.y, a1);
                a1 = fmaf(bv.z, s1.z, a1);
                a1 = fmaf(bv.w, s1.w, a1);
            }
            Wq[(size_t)(r0 + 2 * g) * WQROW + ff * NHS + h * NS + s] = a0;
            Wq[(size_t)(r0 + 2 * g + 1) * WQROW + ff * NHS + h * NS + s] = a1;
        }
    } else {
        int id = bi - 1024;
        int mt = id & 3, lt = (id >> 2) & 7, bh = id >> 5;
        int b = bh >> 3, h = bh & 7;
        int m0 = mt * 64, l0 = lt * 32;
        float (*s_A)[68] = (float(*)[68])raw;
        float (*s_B)[68] = (float(*)[68])(raw + 8704);
        #pragma unroll
        for (int i = 0; i < 2; ++i) {
            int idx = i * 256 + t;
            int row = idx >> 4, c4 = idx & 15;
            float4 v = *(const float4*)(src + (size_t)(b * NL + l0 + row) * ND + h * 64 + c4 * 4);
            *(float4*)&s_A[row][c4 * 4] = v;
        }
        {
            int mr = t >> 2, qd = t & 3;
            const float* kp = src + (size_t)(b * NL + m0 + mr) * ND + h * 64 + qd * 16;
            #pragma unroll
            for (int q = 0; q < 4; ++q) {
                float4 v = *(const float4*)(kp + q * 4);
                int d = qd * 16 + q * 4;
                s_B[d + 0][mr] = v.x;
                s_B[d + 1][mr] = v.y;
                s_B[d + 2][mr] = v.z;
                s_B[d + 3][mr] = v.w;
            }
        }
        __syncthreads();
        int tx = t & 15, ty = t >> 4;
        int ty2 = ty * 2;
        float acc[2][4] = {};
        #pragma unroll
        for (int d = 0; d < 64; ++d) {
            float a0 = s_A[ty2][d];
            float a1 = s_A[ty2 + 1][d];
            float4 bv = *(const float4*)&s_B[d][tx * 4];
            acc[0][0] = fmaf(a0, bv.x, acc[0][0]);
            acc[0][1] = fmaf(a0, bv.y, acc[0][1]);
            acc[0][2] = fmaf(a0, bv.z, acc[0][2]);
            acc[0][3] = fmaf(a0, bv.w, acc[0][3]);
            acc[1][0] = fmaf(a1, bv.x, acc[1][0]);
            acc[1][1] = fmaf(a1, bv.y, acc[1][1]);
            acc[1][2] = fmaf(a1, bv.z, acc[1][2]);
            acc[1][3] = fmaf(a1, bv.w, acc[1][3]);
        }
        #pragma unroll
        for (int i = 0; i < 2; ++i) {
            size_t off = ((size_t)bh * NL + l0 + ty2 + i) * NL + m0 + tx * 4;
            *(float4*)(sbuf + off) = make_float4(acc[i][0] * 0.125f, acc[i][1] * 0.125f,
                                                 acc[i][2] * 0.125f, acc[i][3] * 0.125f);
        }
    }
}

// ---------------------------------------------------------------------------
// K2_FUSED: per row (512 threads): rp logits + base QK + softmax + PV + LN1.
// PV: thread = (d-pair, m-half) -> float2 V loads (512B/wave), halves
// combined via s_pv.
// ---------------------------------------------------------------------------
__global__ __launch_bounds__(512, 4) void k2_fused(const float* __restrict__ src,
                                                   const float* __restrict__ rel_diss,
                                                   const float* __restrict__ rel_dirs,
                                                   const float* __restrict__ Wq,
                                                   const float* __restrict__ sbuf,
                                                   const float* __restrict__ gamma1,
                                                   const float* __restrict__ beta1,
                                                   float* __restrict__ x1buf,
                                                   ushort* __restrict__ x1bf) {
    int row = blockIdx.x;
    int b = row >> 8;
    int l = row & 255;
    int t = threadIdx.x;
    int m = t & 255;
    int hg = t >> 8;
    __shared__ float s_wq[64][76];   // 19456 B
    __shared__ float s_l[NH][NL];    // 8192 B
    __shared__ float s_pv[2][ND];    // 4096 B
    __shared__ float s_red[8];

    const float* wrow = Wq + (size_t)row * WQROW;
    #pragma unroll
    for (int i = 0; i < 9; ++i) {
        int flat = i * 512 + t;
        int r = flat / 72, c = flat - 72 * r;
        s_wq[r][c] = wrow[flat];
    }
    float dist = rel_diss[(size_t)row * NL + m];
    const float* dirp = rel_dirs + ((size_t)row * NL + m) * 3;
    float x = dirp[0], y = dirp[1], z = dirp[2];
    float tcl = fminf(fmaxf(dist * 0.1f, 0.f), 1.f);
    float env = 0.5f * (__cosf(3.14159265358979f * tcl) + 1.f);
    int rc = (int)floorf(dist * 6.3f + 0.5f);
    int rlo = min(max(rc - 6, 0), NR - RWIN);
    float sph[NS];
    sph[0] = 0.28209479177387814f * env;
    sph[1] = 0.4886025119029199f * y * env;
    sph[2] = 0.4886025119029199f * z * env;
    sph[3] = 0.4886025119029199f * x * env;
    sph[4] = 1.0925484305920792f * x * y * env;
    sph[5] = 1.0925484305920792f * y * z * env;
    sph[6] = 0.31539156525252005f * (3.f * z * z - 1.f) * env;
    sph[7] = 1.0925484305920792f * x * z * env;
    sph[8] = 0.5462742152960396f * (x * x - y * y) * env;
    __syncthreads();

    float acc[36];
    #pragma unroll
    for (int i = 0; i < 36; ++i) acc[i] = 0.f;
    #pragma unroll 4
    for (int rw = 0; rw < RWIN; ++rw) {
        int r = rlo + rw;
        float df = dist - r * (10.f / 63.f);
        float rbf = __expf(-df * df * 20.48f);
        const float* wp = &s_wq[r][hg * 36];
        #pragma unroll
        for (int q = 0; q < 9; ++q) {
            float4 w = *(const float4*)(wp + q * 4);
            acc[q * 4 + 0] = fmaf(w.x, rbf, acc[q * 4 + 0]);
            acc[q * 4 + 1] = fmaf(w.y, rbf, acc[q * 4 + 1]);
            acc[q * 4 + 2] = fmaf(w.z, rbf, acc[q * 4 + 2]);
            acc[q * 4 + 3] = fmaf(w.w, rbf, acc[q * 4 + 3]);
        }
    }
    const float* sb = sbuf + (((size_t)(b * NH + hg * 4) * NL) + l) * NL + m;
    #pragma unroll
    for (int hh = 0; hh < 4; ++hh) {
        float sc = 0.f;
        #pragma unroll
        for (int s = 0; s < NS; ++s) sc = fmaf(sph[s], acc[hh * NS + s], sc);
        s_l[hg * 4 + hh][m] = sc + sb[(size_t)hh * NL * NL];
    }
    __syncthreads();

    int wv = t >> 6, lane = t & 63;
    {
        float v0 = s_l[wv][lane], v1 = s_l[wv][lane + 64];
        float v2 = s_l[wv][lane + 128], v3 = s_l[wv][lane + 192];
        float mx = fmaxf(fmaxf(v0, v1), fmaxf(v2, v3));
        #pragma unroll
        for (int off = 32; off; off >>= 1) mx = fmaxf(mx, __shfl_xor(mx, off, 64));
        float p0 = __expf(v0 - mx), p1 = __expf(v1 - mx);
        float p2 = __expf(v2 - mx), p3 = __expf(v3 - mx);
        float sm = p0 + p1 + p2 + p3;
        #pragma unroll
        for (int off = 32; off; off >>= 1) sm += __shfl_xor(sm, off, 64);
        float inv = 1.f / sm;
        s_l[wv][lane] = p0 * inv;
        s_l[wv][lane + 64] = p1 * inv;
        s_l[wv][lane + 128] = p2 * inv;
        s_l[wv][lane + 192] = p3 * inv;
    }
    __syncthreads();

    // --- PV: thread = (d-pair p, m-half) ---
    {
        int p = t & 255, half = t >> 8;
        int d0 = p * 2;
        int h0 = p >> 5;
        float a0 = 0.f, a1 = 0.f, c0 = 0.f, c1 = 0.f;
        const float* vb = src + (size_t)b * NL * ND + (size_t)(half * 128) * ND + d0;
        const float* wl = &s_l[h0][half * 128];
        #pragma unroll 2
        for (int mm = 0; mm < 128; mm += 2) {
            float2 w2v = *(const float2*)(wl + mm);
            float2 v0 = *(const float2*)(vb + (size_t)mm * ND);
            float2 v1 = *(const float2*)(vb + (size_t)(mm + 1) * ND);
            a0 = fmaf(w2v.x, v0.x, a0);
            a1 = fmaf(w2v.x, v0.y, a1);
            c0 = fmaf(w2v.y, v1.x, c0);
            c1 = fmaf(w2v.y, v1.y, c1);
        }
        s_pv[half][d0] = a0 + c0;
        s_pv[half][d0 + 1] = a1 + c1;
    }
    __syncthreads();

    int d = t;
    float av = s_pv[0][d] + s_pv[1][d];
    float x0 = src[(size_t)row * ND + d] + av;
    float mu = block_sum8(x0, s_red) * (1.f / 512.f);
    float e0 = x0 - mu;
    float var = block_sum8(e0 * e0, s_red) * (1.f / 512.f);
    float rs = rsqrtf(var + 1e-5f);
    float o = e0 * rs * gamma1[d] + beta1[d];
    x1buf[(size_t)row * ND + d] = o;
    x1bf[(size_t)row * ND + d] = f2b(o);
}

// ---------------------------------------------------------------------------
// K3 (MFMA): hbf = bf16(leaky_relu(x1bf @ w1t^T + b1))
// ---------------------------------------------------------------------------
__global__ __launch_bounds__(256) void k3_mfma(const ushort* __restrict__ A,
                                               const ushort* __restrict__ Bt,
                                               const float* __restrict__ bias,
                                               ushort* __restrict__ C) {
    const int K = 512, N = 2048;
    int n0 = blockIdx.x * 64, m0 = blockIdx.y * 64;
    int t = threadIdx.x;
    int w = t >> 6, l = t & 63;
    __shared__ ushort As[64][40];
    __shared__ ushort Bs[64][40];
    f32x4 acc0 = {0.f, 0.f, 0.f, 0.f}, acc1 = acc0, acc2 = acc0, acc3 = acc0;
    int sr = t >> 2, sq = (t & 3) * 8;
    const ushort* Ap = A + (size_t)(m0 + sr) * K + sq;
    const ushort* Bp = Bt + (size_t)(n0 + sr) * K + sq;
    int lr = l & 15, lk = (l >> 4) * 8;
    for (int k0 = 0; k0 < K; k0 += 32) {
        uint4 av = *(const uint4*)(Ap + k0);
        uint4 bv = *(const uint4*)(Bp + k0);
        __syncthreads();
        *(uint4*)&As[sr][sq] = av;
        *(uint4*)&Bs[sr][sq] = bv;
        __syncthreads();
        bf16x8 af = *(const bf16x8*)&As[w * 16 + lr][lk];
        bf16x8 b0 = *(const bf16x8*)&Bs[0 * 16 + lr][lk];
        bf16x8 b1v = *(const bf16x8*)&Bs[1 * 16 + lr][lk];
        bf16x8 b2v = *(const bf16x8*)&Bs[2 * 16 + lr][lk];
        bf16x8 b3 = *(const bf16x8*)&Bs[3 * 16 + lr][lk];
        acc0 = __builtin_amdgcn_mfma_f32_16x16x32_bf16(af, b0, acc0, 0, 0, 0);
        acc1 = __builtin_amdgcn_mfma_f32_16x16x32_bf16(af, b1v, acc1, 0, 0, 0);
        acc2 = __builtin_amdgcn_mfma_f32_16x16x32_bf16(af, b2v, acc2, 0, 0, 0);
        acc3 = __builtin_amdgcn_mfma_f32_16x16x32_bf16(af, b3, acc3, 0, 0, 0);
    }
    int rbase = m0 + w * 16 + (l >> 4) * 4;
    #pragma unroll
    for (int e = 0; e < 4; ++e) {
        int row = rbase + e;
        float v;
        int col0 = n0 + lr;
        v = acc0[e] + bias[col0];
        C[(size_t)row * N + col0] = f2b(v >= 0.f ? v : 0.01f * v);
        v = acc1[e] + bias[col0 + 16];
        C[(size_t)row * N + col0 + 16] = f2b(v >= 0.f ? v : 0.01f * v);
        v = acc2[e] + bias[col0 + 32];
        C[(size_t)row * N + col0 + 32] = f2b(v >= 0.f ? v : 0.01f * v);
        v = acc3[e] + bias[col0 + 48];
        C[(size_t)row * N + col0 + 48] = f2b(v >= 0.f ? v : 0.01f * v);
    }
}

// ---------------------------------------------------------------------------
// K4_FUSED (MFMA + last-block LN2): zpart[ks] = hbf chunk @ w2t chunk; the
// 32nd finishing block per 64-row group (8 n-tiles x 4 ks) reduces partials,
// adds x1+b2, LayerNorm2 -> out. Deterministic: fixed read order, one reducer.
// ---------------------------------------------------------------------------
__global__ __launch_bounds__(256) void k4_fused(const ushort* __restrict__ A,
                                                const ushort* __restrict__ Bt,
                                                float* __restrict__ Cp,
                                                const float* __restrict__ x1buf,
                                                const float* __restrict__ b2,
                                                const float* __restrict__ gamma2,
                                                const float* __restrict__ beta2,
                                                float* __restrict__ out,
                                                unsigned* __restrict__ ctr) {
    const int K = 2048, N = 512;
    int n0 = blockIdx.x * 64, m0 = blockIdx.y * 64;
    int ks = blockIdx.z;
    int t = threadIdx.x;
    int w = t >> 6, l = t & 63;
    __shared__ ushort As[64][40];
    __shared__ ushort Bs[64][40];
    __shared__ bool s_last;
    f32x4 acc0 = {0.f, 0.f, 0.f, 0.f}, acc1 = acc0, acc2 = acc0, acc3 = acc0;
    int sr = t >> 2, sq = (t & 3) * 8;
    const ushort* Ap = A + (size_t)(m0 + sr) * K + ks * 512 + sq;
    const ushort* Bp = Bt + (size_t)(n0 + sr) * K + ks * 512 + sq;
    int lr = l & 15, lk = (l >> 4) * 8;
    for (int k0 = 0; k0 < 512; k0 += 32) {
        uint4 av = *(const uint4*)(Ap + k0);
        uint4 bv = *(const uint4*)(Bp + k0);
        __syncthreads();
        *(uint4*)&As[sr][sq] = av;
        *(uint4*)&Bs[sr][sq] = bv;
        __syncthreads();
        bf16x8 af = *(const bf16x8*)&As[w * 16 + lr][lk];
        bf16x8 b0 = *(const bf16x8*)&Bs[0 * 16 + lr][lk];
        bf16x8 b1v = *(const bf16x8*)&Bs[1 * 16 + lr][lk];
        bf16x8 b2v = *(const bf16x8*)&Bs[2 * 16 + lr][lk];
        bf16x8 b3 = *(const bf16x8*)&Bs[3 * 16 + lr][lk];
        acc0 = __builtin_amdgcn_mfma_f32_16x16x32_bf16(af, b0, acc0, 0, 0, 0);
        acc1 = __builtin_amdgcn_mfma_f32_16x16x32_bf16(af, b1v, acc1, 0, 0, 0);
        acc2 = __builtin_amdgcn_mfma_f32_16x16x32_bf16(af, b2v, acc2, 0, 0, 0);
        acc3 = __builtin_amdgcn_mfma_f32_16x16x32_bf16(af, b3, acc3, 0, 0, 0);
    }
    {
        float* op = Cp + ((size_t)ks << 18);
        int rbase = m0 + w * 16 + (l >> 4) * 4;
        #pragma unroll
        for (int e = 0; e < 4; ++e) {
            int row = rbase + e;
            int col0 = n0 + lr;
            op[(size_t)row * N + col0] = acc0[e];
            op[(size_t)row * N + col0 + 16] = acc1[e];
            op[(size_t)row * N + col0 + 32] = acc2[e];
            op[(size_t)row * N + col0 + 48] = acc3[e];
        }
    }
    // ---- last-block reduction: LN2 for rows [m0, m0+64) ----
    __threadfence();          // release our partial stores (device scope)
    __syncthreads();
    if (t == 0) {
        unsigned old = atomicAdd(&ctr[m0 >> 6], 1u);
        s_last = (old == 31u);
    }
    __syncthreads();
    if (!s_last) return;
    __threadfence();          // acquire others' partials

    float4 b2a = *(const float4*)(b2 + l * 4);
    float4 b2b = *(const float4*)(b2 + 256 + l * 4);
    float4 g2a = *(const float4*)(gamma2 + l * 4);
    float4 g2b = *(const float4*)(gamma2 + 256 + l * 4);
    float4 bea = *(const float4*)(beta2 + l * 4);
    float4 beb = *(const float4*)(beta2 + 256 + l * 4);
    #pragma unroll 2
    for (int i = 0; i < 16; ++i) {
        int row = m0 + w * 16 + i;
        size_t base = (size_t)row * ND;
        float4 xA = *(const float4*)(x1buf + base + l * 4);
        float4 xB = *(const float4*)(x1buf + base + 256 + l * 4);
        float z0 = xA.x + b2a.x, z1 = xA.y + b2a.y, z2 = xA.z + b2a.z, z3 = xA.w + b2a.w;
        float z4 = xB.x + b2b.x, z5 = xB.y + b2b.y, z6 = xB.z + b2b.z, z7 = xB.w + b2b.w;
        #pragma unroll
        for (int k = 0; k < 4; ++k) {
            const float* zp = Cp + ((size_t)k << 18) + base;
            float4 pA = *(const float4*)(zp + l * 4);
            float4 pB = *(const float4*)(zp + 256 + l * 4);
            z0 += pA.x; z1 += pA.y; z2 += pA.z; z3 += pA.w;
            z4 += pB.x; z5 += pB.y; z6 += pB.z; z7 += pB.w;
        }
        float s1 = ((z0 + z1) + (z2 + z3)) + ((z4 + z5) + (z6 + z7));
        #pragma unroll
        for (int off = 32; off; off >>= 1) s1 += __shfl_xor(s1, off, 64);
        float mu = s1 * (1.f / 512.f);
        float e0 = z0 - mu, e1 = z1 - mu, e2 = z2 - mu, e3 = z3 - mu;
        float e4 = z4 - mu, e5 = z5 - mu, e6 = z6 - mu, e7 = z7 - mu;
        float s2 = ((e0 * e0 + e1 * e1) + (e2 * e2 + e3 * e3)) +
                   ((e4 * e4 + e5 * e5) + (e6 * e6 + e7 * e7));
        #pragma unroll
        for (int off = 32; off; off >>= 1) s2 += __shfl_xor(s2, off, 64);
        float rs = rsqrtf(s2 * (1.f / 512.f) + 1e-5f);
        float4 oA, oB;
        oA.x = e0 * rs * g2a.x + bea.x;
        oA.y = e1 * rs * g2a.y + bea.y;
        oA.z = e2 * rs * g2a.z + bea.z;
        oA.w = e3 * rs * g2a.w + bea.w;
        oB.x = e4 * rs * g2b.x + beb.x;
        oB.y = e5 * rs * g2b.y + beb.y;
        oB.z = e6 * rs * g2b.z + beb.z;
        oB.w = e7 * rs * g2b.w + beb.w;
        *(float4*)(out + base + l * 4) = oA;
        *(float4*)(out + base + 256 + l * 4) = oB;
    }
}

// ---------------------------------------------------------------------------
extern "C" void kernel_launch(void* const* d_in, const int* in_sizes, int n_in,
                              void* d_out, int out_size, void* d_ws, size_t ws_size,
                              hipStream_t stream) {
    const float* src      = (const float*)d_in[0];
    const float* rel_diss = (const float*)d_in[1];
    const float* rel_dirs = (const float*)d_in[2];
    const float* rp_w     = (const float*)d_in[3];
    // d_in[4] = rp_b: constant over softmax axis -> cancels exactly; skipped
    const float* w1  = (const float*)d_in[5];
    const float* b1  = (const float*)d_in[6];
    const float* w2  = (const float*)d_in[7];
    const float* b2  = (const float*)d_in[8];
    const float* g1  = (const float*)d_in[9];
    const float* be1 = (const float*)d_in[10];
    const float* g2  = (const float*)d_in[11];
    const float* be2 = (const float*)d_in[12];
    float* out = (float*)d_out;

    float* ws = (float*)d_ws;
    float* x1buf = ws;                        // 262144 f
    float* sbuf  = x1buf + 262144;            // 1048576 f
    float* zpart = sbuf + 1048576;            // 1048576 f
    float* Wq    = zpart + 1048576;           // 2359296 f
    ushort* w1t  = (ushort*)(Wq + WQROW * 512);   // 1048576 u16
    ushort* w2t  = w1t + 1048576;                 // 1048576 u16
    ushort* x1bf = w2t + 1048576;                 // 262144 u16
    ushort* hbf  = x1bf + 262144;                 // 1048576 u16
    unsigned* ctr = (unsigned*)(hbf + 1048576);   // 8 u32 (zeroed by k_pre)

    k_pre<<<1536, 256, 0, stream>>>(src, rp_w, w1, w2, Wq, sbuf, w1t, w2t, ctr);
    k2_fused<<<512, 512, 0, stream>>>(src, rel_diss, rel_dirs, Wq, sbuf,
                                      g1, be1, x1buf, x1bf);
    k3_mfma<<<dim3(32, 8), 256, 0, stream>>>(x1bf, w1t, b1, hbf);
    k4_fused<<<dim3(8, 8, 4), 256, 0, stream>>>(hbf, w2t, zpart,
                                                x1buf, b2, g2, be2, out, ctr);
}

// Round 12
// 69.193 us; speedup vs baseline: 4.8597x; 1.6077x over previous
//
#include <hip/hip_runtime.h>

// Problem constants
#define NB 2
#define NL 256
#define ND 512
#define NH 8
#define NR 64
#define NS 9
#define NF 576
#define NHS 72      // NH*NS
#define WQROW 4608  // NR*NHS
#define RWIN 12     // rbf window: terms beyond 5.5*delta < 2e-7 -> negligible

typedef __attribute__((ext_vector_type(8))) short bf16x8;
typedef __attribute__((ext_vector_type(4))) float f32x4;

__device__ __forceinline__ ushort f2b(float f) {   // fp32 -> bf16 RNE
    union { float f; unsigned u; } c; c.f = f;
    unsigned u = c.u;
    return (ushort)((u + 0x7FFF + ((u >> 16) & 1)) >> 16);
}

__device__ __forceinline__ float block_sum8(float v, float* s_red) {
    #pragma unroll
    for (int off = 32; off; off >>= 1) v += __shfl_xor(v, off, 64);
    __syncthreads();
    if ((threadIdx.x & 63) == 0) s_red[threadIdx.x >> 6] = v;
    __syncthreads();
    return ((s_red[0] + s_red[1]) + (s_red[2] + s_red[3])) +
           ((s_red[4] + s_red[5]) + (s_red[6] + s_red[7]));
}

__device__ __forceinline__ float block_sum4(float v, float* s_red) {
    #pragma unroll
    for (int off = 32; off; off >>= 1) v += __shfl_xor(v, off, 64);
    __syncthreads();
    if ((threadIdx.x & 63) == 0) s_red[threadIdx.x >> 6] = v;
    __syncthreads();
    return s_red[0] + s_red[1] + s_red[2] + s_red[3];
}

// ---------------------------------------------------------------------------
// K_PRE: union of 4 independent pre-tasks, one dispatch (1536 blocks):
//   [0,256) t2b(w1)  [256,512) t2b(w2)  [512,1024) k1  [1024,1536) k_qk
// NOTE: no inter-block dataflow inside this dispatch -- all consumers are in
// later dispatches (CDNA4 lesson: cross-block sync via fences/coop-sync costs
// ~60us in L2 coherence on 8 XCDs; dispatch boundaries are cheap).
// ---------------------------------------------------------------------------
__global__ __launch_bounds__(256, 4) void k_pre(const float* __restrict__ src,
                                                const float* __restrict__ rp_w,
                                                const float* __restrict__ w1,
                                                const float* __restrict__ w2,
                                                float* __restrict__ Wq,
                                                float* __restrict__ sbuf,
                                                ushort* __restrict__ w1t,
                                                ushort* __restrict__ w2t) {
    __shared__ __align__(16) char raw[26368];
    int bi = blockIdx.x;
    int t = threadIdx.x;

    if (bi < 512) {
        const float* in; ushort* out; int K, N, bx, by;
        if (bi < 256) { in = w1; out = w1t; K = 512; N = 2048; bx = bi & 31; by = bi >> 5; }
        else { int id = bi - 256; in = w2; out = w2t; K = 2048; N = 512; bx = id & 7; by = id >> 3; }
        float (*tile)[65] = (float(*)[65])raw;
        int n0 = bx * 64, k0 = by * 64;
        int r = t >> 4, c4 = (t & 15) * 4;
        #pragma unroll
        for (int i = 0; i < 4; ++i) {
            int kk = i * 16 + r;
            float4 v = *(const float4*)(in + (size_t)(k0 + kk) * N + n0 + c4);
            tile[kk][c4 + 0] = v.x;
            tile[kk][c4 + 1] = v.y;
            tile[kk][c4 + 2] = v.z;
            tile[kk][c4 + 3] = v.w;
        }
        __syncthreads();
        int rr = t >> 2, cq = (t & 3) * 16;
        ushort buf[16];
        #pragma unroll
        for (int j = 0; j < 16; ++j) buf[j] = f2b(tile[cq + j][rr]);
        ushort* op = out + (size_t)(n0 + rr) * K + k0 + cq;
        *(uint4*)(op) = *(uint4*)&buf[0];
        *(uint4*)(op + 8) = *(uint4*)&buf[8];
    } else if (bi < 1024) {
        int id = bi - 512;
        int rt = id & 63, h = id >> 6;
        float (*s_src)[64] = (float(*)[64])raw;
        float* s_B = (float*)(raw + 2048);
        int r0 = rt * 8;
        {
            int sr = t >> 5;
            int sc = (t & 31) * 2;
            *(float2*)&s_src[sr][sc] =
                *(const float2*)(src + (size_t)(r0 + sr) * ND + h * 64 + sc);
        }
        int ff = t & 63;
        int g  = t >> 6;
        int lr = t >> 2;
        int lq = t & 3;
        const float* bsrc = rp_w + h * 64;
        #pragma unroll 1
        for (int s = 0; s < NS; ++s) {
            __syncthreads();
            #pragma unroll
            for (int i = 0; i < 4; ++i) {
                int slot = i * 4 + lq;
                float4 v = *(const float4*)(bsrc + (size_t)(s * 64 + lr) * ND + slot * 4);
                int sw = slot ^ (lr & 7);
                *(float4*)&s_B[lr * 64 + sw * 4] = v;
            }
            __syncthreads();
            float a0 = 0.f, a1 = 0.f;
            #pragma unroll
            for (int d4 = 0; d4 < 16; ++d4) {
                int sw = d4 ^ (ff & 7);
                float4 bv = *(const float4*)&s_B[ff * 64 + sw * 4];
                float4 s0 = *(const float4*)&s_src[2 * g][d4 * 4];
                float4 s1 = *(const float4*)&s_src[2 * g + 1][d4 * 4];
                a0 = fmaf(bv.x, s0.x, a0);
                a0 = fmaf(bv.y, s0.y, a0);
                a0 = fmaf(bv.z, s0.z, a0);
                a0 = fmaf(bv.w, s0.w, a0);
                a1 = fmaf(bv.x, s1.x, a1);
                a1 = fmaf(bv.y, s1.y, a1);
                a1 = fmaf(bv.z, s1.z, a1);
                a1 = fmaf(bv.w, s1.w, a1);
            }
            Wq[(size_t)(r0 + 2 * g) * WQROW + ff * NHS + h * NS + s] = a0;
            Wq[(size_t)(r0 + 2 * g + 1) * WQROW + ff * NHS + h * NS + s] = a1;
        }
    } else {
        int id = bi - 1024;
        int mt = id & 3, lt = (id >> 2) & 7, bh = id >> 5;
        int b = bh >> 3, h = bh & 7;
        int m0 = mt * 64, l0 = lt * 32;
        float (*s_A)[68] = (float(*)[68])raw;
        float (*s_B)[68] = (float(*)[68])(raw + 8704);
        #pragma unroll
        for (int i = 0; i < 2; ++i) {
            int idx = i * 256 + t;
            int row = idx >> 4, c4 = idx & 15;
            float4 v = *(const float4*)(src + (size_t)(b * NL + l0 + row) * ND + h * 64 + c4 * 4);
            *(float4*)&s_A[row][c4 * 4] = v;
        }
        {
            int mr = t >> 2, qd = t & 3;
            const float* kp = src + (size_t)(b * NL + m0 + mr) * ND + h * 64 + qd * 16;
            #pragma unroll
            for (int q = 0; q < 4; ++q) {
                float4 v = *(const float4*)(kp + q * 4);
                int d = qd * 16 + q * 4;
                s_B[d + 0][mr] = v.x;
                s_B[d + 1][mr] = v.y;
                s_B[d + 2][mr] = v.z;
                s_B[d + 3][mr] = v.w;
            }
        }
        __syncthreads();
        int tx = t & 15, ty = t >> 4;
        int ty2 = ty * 2;
        float acc[2][4] = {};
        #pragma unroll
        for (int d = 0; d < 64; ++d) {
            float a0 = s_A[ty2][d];
            float a1 = s_A[ty2 + 1][d];
            float4 bv = *(const float4*)&s_B[d][tx * 4];
            acc[0][0] = fmaf(a0, bv.x, acc[0][0]);
            acc[0][1] = fmaf(a0, bv.y, acc[0][1]);
            acc[0][2] = fmaf(a0, bv.z, acc[0][2]);
            acc[0][3] = fmaf(a0, bv.w, acc[0][3]);
            acc[1][0] = fmaf(a1, bv.x, acc[1][0]);
            acc[1][1] = fmaf(a1, bv.y, acc[1][1]);
            acc[1][2] = fmaf(a1, bv.z, acc[1][2]);
            acc[1][3] = fmaf(a1, bv.w, acc[1][3]);
        }
        #pragma unroll
        for (int i = 0; i < 2; ++i) {
            size_t off = ((size_t)bh * NL + l0 + ty2 + i) * NL + m0 + tx * 4;
            *(float4*)(sbuf + off) = make_float4(acc[i][0] * 0.125f, acc[i][1] * 0.125f,
                                                 acc[i][2] * 0.125f, acc[i][3] * 0.125f);
        }
    }
}

// ---------------------------------------------------------------------------
// K2_FUSED: per row (512 threads): rp logits + base QK + softmax + PV + LN1.
// PV: thread = (d-pair, m-half) -> float2 V loads, halves combined via s_pv.
// ---------------------------------------------------------------------------
__global__ __launch_bounds__(512, 4) void k2_fused(const float* __restrict__ src,
                                                   const float* __restrict__ rel_diss,
                                                   const float* __restrict__ rel_dirs,
                                                   const float* __restrict__ Wq,
                                                   const float* __restrict__ sbuf,
                                                   const float* __restrict__ gamma1,
                                                   const float* __restrict__ beta1,
                                                   float* __restrict__ x1buf,
                                                   ushort* __restrict__ x1bf) {
    int row = blockIdx.x;
    int b = row >> 8;
    int l = row & 255;
    int t = threadIdx.x;
    int m = t & 255;
    int hg = t >> 8;
    __shared__ float s_wq[64][76];   // 19456 B
    __shared__ float s_l[NH][NL];    // 8192 B
    __shared__ float s_pv[2][ND];    // 4096 B
    __shared__ float s_red[8];

    const float* wrow = Wq + (size_t)row * WQROW;
    #pragma unroll
    for (int i = 0; i < 9; ++i) {
        int flat = i * 512 + t;
        int r = flat / 72, c = flat - 72 * r;
        s_wq[r][c] = wrow[flat];
    }
    float dist = rel_diss[(size_t)row * NL + m];
    const float* dirp = rel_dirs + ((size_t)row * NL + m) * 3;
    float x = dirp[0], y = dirp[1], z = dirp[2];
    float tcl = fminf(fmaxf(dist * 0.1f, 0.f), 1.f);
    float env = 0.5f * (__cosf(3.14159265358979f * tcl) + 1.f);
    int rc = (int)floorf(dist * 6.3f + 0.5f);
    int rlo = min(max(rc - 6, 0), NR - RWIN);
    float sph[NS];
    sph[0] = 0.28209479177387814f * env;
    sph[1] = 0.4886025119029199f * y * env;
    sph[2] = 0.4886025119029199f * z * env;
    sph[3] = 0.4886025119029199f * x * env;
    sph[4] = 1.0925484305920792f * x * y * env;
    sph[5] = 1.0925484305920792f * y * z * env;
    sph[6] = 0.31539156525252005f * (3.f * z * z - 1.f) * env;
    sph[7] = 1.0925484305920792f * x * z * env;
    sph[8] = 0.5462742152960396f * (x * x - y * y) * env;
    __syncthreads();

    float acc[36];
    #pragma unroll
    for (int i = 0; i < 36; ++i) acc[i] = 0.f;
    #pragma unroll 4
    for (int rw = 0; rw < RWIN; ++rw) {
        int r = rlo + rw;
        float df = dist - r * (10.f / 63.f);
        float rbf = __expf(-df * df * 20.48f);
        const float* wp = &s_wq[r][hg * 36];
        #pragma unroll
        for (int q = 0; q < 9; ++q) {
            float4 w = *(const float4*)(wp + q * 4);
            acc[q * 4 + 0] = fmaf(w.x, rbf, acc[q * 4 + 0]);
            acc[q * 4 + 1] = fmaf(w.y, rbf, acc[q * 4 + 1]);
            acc[q * 4 + 2] = fmaf(w.z, rbf, acc[q * 4 + 2]);
            acc[q * 4 + 3] = fmaf(w.w, rbf, acc[q * 4 + 3]);
        }
    }
    const float* sb = sbuf + (((size_t)(b * NH + hg * 4) * NL) + l) * NL + m;
    #pragma unroll
    for (int hh = 0; hh < 4; ++hh) {
        float sc = 0.f;
        #pragma unroll
        for (int s = 0; s < NS; ++s) sc = fmaf(sph[s], acc[hh * NS + s], sc);
        s_l[hg * 4 + hh][m] = sc + sb[(size_t)hh * NL * NL];
    }
    __syncthreads();

    int wv = t >> 6, lane = t & 63;
    {
        float v0 = s_l[wv][lane], v1 = s_l[wv][lane + 64];
        float v2 = s_l[wv][lane + 128], v3 = s_l[wv][lane + 192];
        float mx = fmaxf(fmaxf(v0, v1), fmaxf(v2, v3));
        #pragma unroll
        for (int off = 32; off; off >>= 1) mx = fmaxf(mx, __shfl_xor(mx, off, 64));
        float p0 = __expf(v0 - mx), p1 = __expf(v1 - mx);
        float p2 = __expf(v2 - mx), p3 = __expf(v3 - mx);
        float sm = p0 + p1 + p2 + p3;
        #pragma unroll
        for (int off = 32; off; off >>= 1) sm += __shfl_xor(sm, off, 64);
        float inv = 1.f / sm;
        s_l[wv][lane] = p0 * inv;
        s_l[wv][lane + 64] = p1 * inv;
        s_l[wv][lane + 128] = p2 * inv;
        s_l[wv][lane + 192] = p3 * inv;
    }
    __syncthreads();

    // --- PV: thread = (d-pair p, m-half) ---
    {
        int p = t & 255, half = t >> 8;
        int d0 = p * 2;
        int h0 = p >> 5;
        float a0 = 0.f, a1 = 0.f, c0 = 0.f, c1 = 0.f;
        const float* vb = src + (size_t)b * NL * ND + (size_t)(half * 128) * ND + d0;
        const float* wl = &s_l[h0][half * 128];
        #pragma unroll 2
        for (int mm = 0; mm < 128; mm += 2) {
            float2 w2v = *(const float2*)(wl + mm);
            float2 v0 = *(const float2*)(vb + (size_t)mm * ND);
            float2 v1 = *(const float2*)(vb + (size_t)(mm + 1) * ND);
            a0 = fmaf(w2v.x, v0.x, a0);
            a1 = fmaf(w2v.x, v0.y, a1);
            c0 = fmaf(w2v.y, v1.x, c0);
            c1 = fmaf(w2v.y, v1.y, c1);
        }
        s_pv[half][d0] = a0 + c0;
        s_pv[half][d0 + 1] = a1 + c1;
    }
    __syncthreads();

    int d = t;
    float av = s_pv[0][d] + s_pv[1][d];
    float x0 = src[(size_t)row * ND + d] + av;
    float mu = block_sum8(x0, s_red) * (1.f / 512.f);
    float e0 = x0 - mu;
    float var = block_sum8(e0 * e0, s_red) * (1.f / 512.f);
    float rs = rsqrtf(var + 1e-5f);
    float o = e0 * rs * gamma1[d] + beta1[d];
    x1buf[(size_t)row * ND + d] = o;
    x1bf[(size_t)row * ND + d] = f2b(o);
}

// ---------------------------------------------------------------------------
// K3 (MFMA): hbf = bf16(leaky_relu(x1bf @ w1t^T + b1))
// ---------------------------------------------------------------------------
__global__ __launch_bounds__(256) void k3_mfma(const ushort* __restrict__ A,
                                               const ushort* __restrict__ Bt,
                                               const float* __restrict__ bias,
                                               ushort* __restrict__ C) {
    const int K = 512, N = 2048;
    int n0 = blockIdx.x * 64, m0 = blockIdx.y * 64;
    int t = threadIdx.x;
    int w = t >> 6, l = t & 63;
    __shared__ ushort As[64][40];
    __shared__ ushort Bs[64][40];
    f32x4 acc0 = {0.f, 0.f, 0.f, 0.f}, acc1 = acc0, acc2 = acc0, acc3 = acc0;
    int sr = t >> 2, sq = (t & 3) * 8;
    const ushort* Ap = A + (size_t)(m0 + sr) * K + sq;
    const ushort* Bp = Bt + (size_t)(n0 + sr) * K + sq;
    int lr = l & 15, lk = (l >> 4) * 8;
    for (int k0 = 0; k0 < K; k0 += 32) {
        uint4 av = *(const uint4*)(Ap + k0);
        uint4 bv = *(const uint4*)(Bp + k0);
        __syncthreads();
        *(uint4*)&As[sr][sq] = av;
        *(uint4*)&Bs[sr][sq] = bv;
        __syncthreads();
        bf16x8 af = *(const bf16x8*)&As[w * 16 + lr][lk];
        bf16x8 b0 = *(const bf16x8*)&Bs[0 * 16 + lr][lk];
        bf16x8 b1v = *(const bf16x8*)&Bs[1 * 16 + lr][lk];
        bf16x8 b2v = *(const bf16x8*)&Bs[2 * 16 + lr][lk];
        bf16x8 b3 = *(const bf16x8*)&Bs[3 * 16 + lr][lk];
        acc0 = __builtin_amdgcn_mfma_f32_16x16x32_bf16(af, b0, acc0, 0, 0, 0);
        acc1 = __builtin_amdgcn_mfma_f32_16x16x32_bf16(af, b1v, acc1, 0, 0, 0);
        acc2 = __builtin_amdgcn_mfma_f32_16x16x32_bf16(af, b2v, acc2, 0, 0, 0);
        acc3 = __builtin_amdgcn_mfma_f32_16x16x32_bf16(af, b3, acc3, 0, 0, 0);
    }
    int rbase = m0 + w * 16 + (l >> 4) * 4;
    #pragma unroll
    for (int e = 0; e < 4; ++e) {
        int row = rbase + e;
        float v;
        int col0 = n0 + lr;
        v = acc0[e] + bias[col0];
        C[(size_t)row * N + col0] = f2b(v >= 0.f ? v : 0.01f * v);
        v = acc1[e] + bias[col0 + 16];
        C[(size_t)row * N + col0 + 16] = f2b(v >= 0.f ? v : 0.01f * v);
        v = acc2[e] + bias[col0 + 32];
        C[(size_t)row * N + col0 + 32] = f2b(v >= 0.f ? v : 0.01f * v);
        v = acc3[e] + bias[col0 + 48];
        C[(size_t)row * N + col0 + 48] = f2b(v >= 0.f ? v : 0.01f * v);
    }
}

// ---------------------------------------------------------------------------
// K4 (MFMA): zpart[ks] = hbf[:, ks*512:+512] @ w2t^T chunk -> fp32
// ---------------------------------------------------------------------------
__global__ __launch_bounds__(256) void k4_mfma(const ushort* __restrict__ A,
                                               const ushort* __restrict__ Bt,
                                               float* __restrict__ Cp) {
    const int K = 2048, N = 512;
    int n0 = blockIdx.x * 64, m0 = blockIdx.y * 64;
    int ks = blockIdx.z;
    int t = threadIdx.x;
    int w = t >> 6, l = t & 63;
    __shared__ ushort As[64][40];
    __shared__ ushort Bs[64][40];
    f32x4 acc0 = {0.f, 0.f, 0.f, 0.f}, acc1 = acc0, acc2 = acc0, acc3 = acc0;
    int sr = t >> 2, sq = (t & 3) * 8;
    const ushort* Ap = A + (size_t)(m0 + sr) * K + ks * 512 + sq;
    const ushort* Bp = Bt + (size_t)(n0 + sr) * K + ks * 512 + sq;
    int lr = l & 15, lk = (l >> 4) * 8;
    for (int k0 = 0; k0 < 512; k0 += 32) {
        uint4 av = *(const uint4*)(Ap + k0);
        uint4 bv = *(const uint4*)(Bp + k0);
        __syncthreads();
        *(uint4*)&As[sr][sq] = av;
        *(uint4*)&Bs[sr][sq] = bv;
        __syncthreads();
        bf16x8 af = *(const bf16x8*)&As[w * 16 + lr][lk];
        bf16x8 b0 = *(const bf16x8*)&Bs[0 * 16 + lr][lk];
        bf16x8 b1v = *(const bf16x8*)&Bs[1 * 16 + lr][lk];
        bf16x8 b2v = *(const bf16x8*)&Bs[2 * 16 + lr][lk];
        bf16x8 b3 = *(const bf16x8*)&Bs[3 * 16 + lr][lk];
        acc0 = __builtin_amdgcn_mfma_f32_16x16x32_bf16(af, b0, acc0, 0, 0, 0);
        acc1 = __builtin_amdgcn_mfma_f32_16x16x32_bf16(af, b1v, acc1, 0, 0, 0);
        acc2 = __builtin_amdgcn_mfma_f32_16x16x32_bf16(af, b2v, acc2, 0, 0, 0);
        acc3 = __builtin_amdgcn_mfma_f32_16x16x32_bf16(af, b3, acc3, 0, 0, 0);
    }
    float* out = Cp + ((size_t)ks << 18);
    int rbase = m0 + w * 16 + (l >> 4) * 4;
    #pragma unroll
    for (int e = 0; e < 4; ++e) {
        int row = rbase + e;
        int col0 = n0 + lr;
        out[(size_t)row * N + col0] = acc0[e];
        out[(size_t)row * N + col0 + 16] = acc1[e];
        out[(size_t)row * N + col0 + 32] = acc2[e];
        out[(size_t)row * N + col0 + 48] = acc3[e];
    }
}

// ---------------------------------------------------------------------------
// K5: z = x1 + b2 + sum_ks zpart[ks]; out = LayerNorm2(z)
// ---------------------------------------------------------------------------
__global__ __launch_bounds__(256) void k5_final(const float* __restrict__ x1buf,
                                                const float* __restrict__ zpart,
                                                const float* __restrict__ b2,
                                                const float* __restrict__ gamma2,
                                                const float* __restrict__ beta2,
                                                float* __restrict__ out) {
    int row = blockIdx.x;
    int t = threadIdx.x;
    int d0 = t * 2;
    __shared__ float s_red[8];
    size_t off = (size_t)row * ND + d0;
    float2 v = *(const float2*)(x1buf + off);
    float2 bb = *(const float2*)(b2 + d0);
    float z0 = v.x + bb.x, z1 = v.y + bb.y;
    #pragma unroll
    for (int ks = 0; ks < 4; ++ks) {
        float2 p = *(const float2*)(zpart + ((size_t)ks << 18) + off);
        z0 += p.x;
        z1 += p.y;
    }
    float mu = block_sum4(z0 + z1, s_red) * (1.f / 512.f);
    float e0 = z0 - mu, e1 = z1 - mu;
    float var = block_sum4(e0 * e0 + e1 * e1, s_red) * (1.f / 512.f);
    float rs = rsqrtf(var + 1e-5f);
    float2 g = *(const float2*)(gamma2 + d0), be = *(const float2*)(beta2 + d0);
    *(float2*)(out + off) = make_float2(e0 * rs * g.x + be.x, e1 * rs * g.y + be.y);
}

// ---------------------------------------------------------------------------
extern "C" void kernel_launch(void* const* d_in, const int* in_sizes, int n_in,
                              void* d_out, int out_size, void* d_ws, size_t ws_size,
                              hipStream_t stream) {
    const float* src      = (const float*)d_in[0];
    const float* rel_diss = (const float*)d_in[1];
    const float* rel_dirs = (const float*)d_in[2];
    const float* rp_w     = (const float*)d_in[3];
    // d_in[4] = rp_b: constant over softmax axis -> cancels exactly; skipped
    const float* w1  = (const float*)d_in[5];
    const float* b1  = (const float*)d_in[6];
    const float* w2  = (const float*)d_in[7];
    const float* b2  = (const float*)d_in[8];
    const float* g1  = (const float*)d_in[9];
    const float* be1 = (const float*)d_in[10];
    const float* g2  = (const float*)d_in[11];
    const float* be2 = (const float*)d_in[12];
    float* out = (float*)d_out;

    float* ws = (float*)d_ws;
    float* x1buf = ws;                        // 262144 f
    float* sbuf  = x1buf + 262144;            // 1048576 f
    float* zpart = sbuf + 1048576;            // 1048576 f
    float* Wq    = zpart + 1048576;           // 2359296 f
    ushort* w1t  = (ushort*)(Wq + WQROW * 512);   // 1048576 u16
    ushort* w2t  = w1t + 1048576;                 // 1048576 u16
    ushort* x1bf = w2t + 1048576;                 // 262144 u16
    ushort* hbf  = x1bf + 262144;                 // 1048576 u16

    k_pre<<<1536, 256, 0, stream>>>(src, rp_w, w1, w2, Wq, sbuf, w1t, w2t);
    k2_fused<<<512, 512, 0, stream>>>(src, rel_diss, rel_dirs, Wq, sbuf,
                                      g1, be1, x1buf, x1bf);
    k3_mfma<<<dim3(32, 8), 256, 0, stream>>>(x1bf, w1t, b1, hbf);
    k4_mfma<<<dim3(8, 8, 4), 256, 0, stream>>>(hbf, w2t, zpart);
    k5_final<<<512, 256, 0, stream>>>(x1buf, zpart, b2, g2, be2, out);
}

// Round 13
// 64.632 us; speedup vs baseline: 5.2026x; 1.0706x over previous
//
#include <hip/hip_runtime.h>

// Problem constants
#define NB 2
#define NL 256
#define ND 512
#define NH 8
#define NR 64
#define NS 9
#define NF 576
#define NHS 72      // NH*NS
#define WQROW 4608  // NR*NHS
#define RWIN 12     // rbf window: terms beyond 5.5*delta < 2e-7 -> negligible

typedef __attribute__((ext_vector_type(8))) short bf16x8;
typedef __attribute__((ext_vector_type(4))) float f32x4;

__device__ __forceinline__ ushort f2b(float f) {   // fp32 -> bf16 RNE
    union { float f; unsigned u; } c; c.f = f;
    unsigned u = c.u;
    return (ushort)((u + 0x7FFF + ((u >> 16) & 1)) >> 16);
}
__device__ __forceinline__ float b2f(ushort u) {   // bf16 -> fp32
    union { unsigned u; float f; } c; c.u = ((unsigned)u) << 16;
    return c.f;
}
__device__ __forceinline__ float b2f_lo(unsigned u) {
    union { unsigned u; float f; } c; c.u = u << 16;
    return c.f;
}
__device__ __forceinline__ float b2f_hi(unsigned u) {
    union { unsigned u; float f; } c; c.u = u & 0xffff0000u;
    return c.f;
}

__device__ __forceinline__ float block_sum8(float v, float* s_red) {
    #pragma unroll
    for (int off = 32; off; off >>= 1) v += __shfl_xor(v, off, 64);
    __syncthreads();
    if ((threadIdx.x & 63) == 0) s_red[threadIdx.x >> 6] = v;
    __syncthreads();
    return ((s_red[0] + s_red[1]) + (s_red[2] + s_red[3])) +
           ((s_red[4] + s_red[5]) + (s_red[6] + s_red[7]));
}

__device__ __forceinline__ float block_sum4(float v, float* s_red) {
    #pragma unroll
    for (int off = 32; off; off >>= 1) v += __shfl_xor(v, off, 64);
    __syncthreads();
    if ((threadIdx.x & 63) == 0) s_red[threadIdx.x >> 6] = v;
    __syncthreads();
    return s_red[0] + s_red[1] + s_red[2] + s_red[3];
}

// ---------------------------------------------------------------------------
// K_PRE: union of 5 independent pre-tasks, one dispatch (1600 blocks):
//   [0,256) t2b(w1)  [256,512) t2b(w2)  [512,1024) k1  [1024,1536) k_qk
//   [1536,1600) src->bf16 convert
// No inter-block dataflow inside this dispatch (CDNA4: fences/coop-sync cost
// ~60us in cross-XCD L2 coherence; dispatch boundaries are cheap).
// ---------------------------------------------------------------------------
__global__ __launch_bounds__(256, 4) void k_pre(const float* __restrict__ src,
                                                const float* __restrict__ rp_w,
                                                const float* __restrict__ w1,
                                                const float* __restrict__ w2,
                                                float* __restrict__ Wq,
                                                ushort* __restrict__ sbuf_bf,
                                                ushort* __restrict__ w1t,
                                                ushort* __restrict__ w2t,
                                                ushort* __restrict__ src_bf) {
    __shared__ __align__(16) char raw[26368];
    int bi = blockIdx.x;
    int t = threadIdx.x;

    if (bi < 512) {
        const float* in; ushort* out; int K, N, bx, by;
        if (bi < 256) { in = w1; out = w1t; K = 512; N = 2048; bx = bi & 31; by = bi >> 5; }
        else { int id = bi - 256; in = w2; out = w2t; K = 2048; N = 512; bx = id & 7; by = id >> 3; }
        float (*tile)[65] = (float(*)[65])raw;
        int n0 = bx * 64, k0 = by * 64;
        int r = t >> 4, c4 = (t & 15) * 4;
        #pragma unroll
        for (int i = 0; i < 4; ++i) {
            int kk = i * 16 + r;
            float4 v = *(const float4*)(in + (size_t)(k0 + kk) * N + n0 + c4);
            tile[kk][c4 + 0] = v.x;
            tile[kk][c4 + 1] = v.y;
            tile[kk][c4 + 2] = v.z;
            tile[kk][c4 + 3] = v.w;
        }
        __syncthreads();
        int rr = t >> 2, cq = (t & 3) * 16;
        ushort buf[16];
        #pragma unroll
        for (int j = 0; j < 16; ++j) buf[j] = f2b(tile[cq + j][rr]);
        ushort* op = out + (size_t)(n0 + rr) * K + k0 + cq;
        *(uint4*)(op) = *(uint4*)&buf[0];
        *(uint4*)(op + 8) = *(uint4*)&buf[8];
    } else if (bi < 1024) {
        int id = bi - 512;
        int rt = id & 63, h = id >> 6;
        float (*s_src)[64] = (float(*)[64])raw;
        float* s_B = (float*)(raw + 2048);
        int r0 = rt * 8;
        {
            int sr = t >> 5;
            int sc = (t & 31) * 2;
            *(float2*)&s_src[sr][sc] =
                *(const float2*)(src + (size_t)(r0 + sr) * ND + h * 64 + sc);
        }
        int ff = t & 63;
        int g  = t >> 6;
        int lr = t >> 2;
        int lq = t & 3;
        const float* bsrc = rp_w + h * 64;
        #pragma unroll 1
        for (int s = 0; s < NS; ++s) {
            __syncthreads();
            #pragma unroll
            for (int i = 0; i < 4; ++i) {
                int slot = i * 4 + lq;
                float4 v = *(const float4*)(bsrc + (size_t)(s * 64 + lr) * ND + slot * 4);
                int sw = slot ^ (lr & 7);
                *(float4*)&s_B[lr * 64 + sw * 4] = v;
            }
            __syncthreads();
            float a0 = 0.f, a1 = 0.f;
            #pragma unroll
            for (int d4 = 0; d4 < 16; ++d4) {
                int sw = d4 ^ (ff & 7);
                float4 bv = *(const float4*)&s_B[ff * 64 + sw * 4];
                float4 s0 = *(const float4*)&s_src[2 * g][d4 * 4];
                float4 s1 = *(const float4*)&s_src[2 * g + 1][d4 * 4];
                a0 = fmaf(bv.x, s0.x, a0);
                a0 = fmaf(bv.y, s0.y, a0);
                a0 = fmaf(bv.z, s0.z, a0);
                a0 = fmaf(bv.w, s0.w, a0);
                a1 = fmaf(bv.x, s1.x, a1);
                a1 = fmaf(bv.y, s1.y, a1);
                a1 = fmaf(bv.z, s1.z, a1);
                a1 = fmaf(bv.w, s1.w, a1);
            }
            Wq[(size_t)(r0 + 2 * g) * WQROW + ff * NHS + h * NS + s] = a0;
            Wq[(size_t)(r0 + 2 * g + 1) * WQROW + ff * NHS + h * NS + s] = a1;
        }
    } else if (bi < 1536) {
        int id = bi - 1024;
        int mt = id & 3, lt = (id >> 2) & 7, bh = id >> 5;
        int b = bh >> 3, h = bh & 7;
        int m0 = mt * 64, l0 = lt * 32;
        float (*s_A)[68] = (float(*)[68])raw;
        float (*s_B)[68] = (float(*)[68])(raw + 8704);
        #pragma unroll
        for (int i = 0; i < 2; ++i) {
            int idx = i * 256 + t;
            int row = idx >> 4, c4 = idx & 15;
            float4 v = *(const float4*)(src + (size_t)(b * NL + l0 + row) * ND + h * 64 + c4 * 4);
            *(float4*)&s_A[row][c4 * 4] = v;
        }
        {
            int mr = t >> 2, qd = t & 3;
            const float* kp = src + (size_t)(b * NL + m0 + mr) * ND + h * 64 + qd * 16;
            #pragma unroll
            for (int q = 0; q < 4; ++q) {
                float4 v = *(const float4*)(kp + q * 4);
                int d = qd * 16 + q * 4;
                s_B[d + 0][mr] = v.x;
                s_B[d + 1][mr] = v.y;
                s_B[d + 2][mr] = v.z;
                s_B[d + 3][mr] = v.w;
            }
        }
        __syncthreads();
        int tx = t & 15, ty = t >> 4;
        int ty2 = ty * 2;
        float acc[2][4] = {};
        #pragma unroll
        for (int d = 0; d < 64; ++d) {
            float a0 = s_A[ty2][d];
            float a1 = s_A[ty2 + 1][d];
            float4 bv = *(const float4*)&s_B[d][tx * 4];
            acc[0][0] = fmaf(a0, bv.x, acc[0][0]);
            acc[0][1] = fmaf(a0, bv.y, acc[0][1]);
            acc[0][2] = fmaf(a0, bv.z, acc[0][2]);
            acc[0][3] = fmaf(a0, bv.w, acc[0][3]);
            acc[1][0] = fmaf(a1, bv.x, acc[1][0]);
            acc[1][1] = fmaf(a1, bv.y, acc[1][1]);
            acc[1][2] = fmaf(a1, bv.z, acc[1][2]);
            acc[1][3] = fmaf(a1, bv.w, acc[1][3]);
        }
        // write base logits as bf16 (halves k2's read traffic)
        #pragma unroll
        for (int i = 0; i < 2; ++i) {
            size_t off = ((size_t)bh * NL + l0 + ty2 + i) * NL + m0 + tx * 4;
            unsigned p0 = (unsigned)f2b(acc[i][0] * 0.125f) |
                          ((unsigned)f2b(acc[i][1] * 0.125f) << 16);
            unsigned p1 = (unsigned)f2b(acc[i][2] * 0.125f) |
                          ((unsigned)f2b(acc[i][3] * 0.125f) << 16);
            uint2 pk; pk.x = p0; pk.y = p1;
            *(uint2*)(sbuf_bf + off) = pk;
        }
    } else {
        // ---- src -> bf16 convert: 64 blocks x 256 thr x 16 elems ----
        int id = bi - 1536;
        size_t base = (size_t)id * 4096 + (size_t)t * 16;
        const float4* ip = (const float4*)(src + base);
        float4 v0 = ip[0], v1 = ip[1], v2 = ip[2], v3 = ip[3];
        ushort o[16];
        o[0] = f2b(v0.x); o[1] = f2b(v0.y); o[2] = f2b(v0.z); o[3] = f2b(v0.w);
        o[4] = f2b(v1.x); o[5] = f2b(v1.y); o[6] = f2b(v1.z); o[7] = f2b(v1.w);
        o[8] = f2b(v2.x); o[9] = f2b(v2.y); o[10] = f2b(v2.z); o[11] = f2b(v2.w);
        o[12] = f2b(v3.x); o[13] = f2b(v3.y); o[14] = f2b(v3.z); o[15] = f2b(v3.w);
        *(uint4*)(src_bf + base) = *(uint4*)&o[0];
        *(uint4*)(src_bf + base + 8) = *(uint4*)&o[8];
    }
}

// ---------------------------------------------------------------------------
// K2_FUSED: per row (512 threads): rp logits + base QK (bf16 sbuf) + softmax
// + PV (bf16 V from src_bf, fp32 accum) + residual(fp32 src) + LN1.
// ---------------------------------------------------------------------------
__global__ __launch_bounds__(512, 4) void k2_fused(const float* __restrict__ src,
                                                   const ushort* __restrict__ src_bf,
                                                   const float* __restrict__ rel_diss,
                                                   const float* __restrict__ rel_dirs,
                                                   const float* __restrict__ Wq,
                                                   const ushort* __restrict__ sbuf_bf,
                                                   const float* __restrict__ gamma1,
                                                   const float* __restrict__ beta1,
                                                   float* __restrict__ x1buf,
                                                   ushort* __restrict__ x1bf) {
    int row = blockIdx.x;
    int b = row >> 8;
    int l = row & 255;
    int t = threadIdx.x;
    int m = t & 255;
    int hg = t >> 8;
    __shared__ float s_wq[64][76];   // 19456 B
    __shared__ float s_l[NH][NL];    // 8192 B
    __shared__ float s_pv[2][ND];    // 4096 B
    __shared__ float s_red[8];

    const float* wrow = Wq + (size_t)row * WQROW;
    #pragma unroll
    for (int i = 0; i < 9; ++i) {
        int flat = i * 512 + t;
        int r = flat / 72, c = flat - 72 * r;
        s_wq[r][c] = wrow[flat];
    }
    float dist = rel_diss[(size_t)row * NL + m];
    const float* dirp = rel_dirs + ((size_t)row * NL + m) * 3;
    float x = dirp[0], y = dirp[1], z = dirp[2];
    float tcl = fminf(fmaxf(dist * 0.1f, 0.f), 1.f);
    float env = 0.5f * (__cosf(3.14159265358979f * tcl) + 1.f);
    int rc = (int)floorf(dist * 6.3f + 0.5f);
    int rlo = min(max(rc - 6, 0), NR - RWIN);
    float sph[NS];
    sph[0] = 0.28209479177387814f * env;
    sph[1] = 0.4886025119029199f * y * env;
    sph[2] = 0.4886025119029199f * z * env;
    sph[3] = 0.4886025119029199f * x * env;
    sph[4] = 1.0925484305920792f * x * y * env;
    sph[5] = 1.0925484305920792f * y * z * env;
    sph[6] = 0.31539156525252005f * (3.f * z * z - 1.f) * env;
    sph[7] = 1.0925484305920792f * x * z * env;
    sph[8] = 0.5462742152960396f * (x * x - y * y) * env;
    __syncthreads();

    float acc[36];
    #pragma unroll
    for (int i = 0; i < 36; ++i) acc[i] = 0.f;
    #pragma unroll 4
    for (int rw = 0; rw < RWIN; ++rw) {
        int r = rlo + rw;
        float df = dist - r * (10.f / 63.f);
        float rbf = __expf(-df * df * 20.48f);
        const float* wp = &s_wq[r][hg * 36];
        #pragma unroll
        for (int q = 0; q < 9; ++q) {
            float4 w = *(const float4*)(wp + q * 4);
            acc[q * 4 + 0] = fmaf(w.x, rbf, acc[q * 4 + 0]);
            acc[q * 4 + 1] = fmaf(w.y, rbf, acc[q * 4 + 1]);
            acc[q * 4 + 2] = fmaf(w.z, rbf, acc[q * 4 + 2]);
            acc[q * 4 + 3] = fmaf(w.w, rbf, acc[q * 4 + 3]);
        }
    }
    const ushort* sb = sbuf_bf + (((size_t)(b * NH + hg * 4) * NL) + l) * NL + m;
    #pragma unroll
    for (int hh = 0; hh < 4; ++hh) {
        float sc = 0.f;
        #pragma unroll
        for (int s = 0; s < NS; ++s) sc = fmaf(sph[s], acc[hh * NS + s], sc);
        s_l[hg * 4 + hh][m] = sc + b2f(sb[(size_t)hh * NL * NL]);
    }
    __syncthreads();

    int wv = t >> 6, lane = t & 63;
    {
        float v0 = s_l[wv][lane], v1 = s_l[wv][lane + 64];
        float v2 = s_l[wv][lane + 128], v3 = s_l[wv][lane + 192];
        float mx = fmaxf(fmaxf(v0, v1), fmaxf(v2, v3));
        #pragma unroll
        for (int off = 32; off; off >>= 1) mx = fmaxf(mx, __shfl_xor(mx, off, 64));
        float p0 = __expf(v0 - mx), p1 = __expf(v1 - mx);
        float p2 = __expf(v2 - mx), p3 = __expf(v3 - mx);
        float sm = p0 + p1 + p2 + p3;
        #pragma unroll
        for (int off = 32; off; off >>= 1) sm += __shfl_xor(sm, off, 64);
        float inv = 1.f / sm;
        s_l[wv][lane] = p0 * inv;
        s_l[wv][lane + 64] = p1 * inv;
        s_l[wv][lane + 128] = p2 * inv;
        s_l[wv][lane + 192] = p3 * inv;
    }
    __syncthreads();

    // --- PV: thread = (d-pair p, m-half), V read as bf16 pairs ---
    {
        int p = t & 255, half = t >> 8;
        int d0 = p * 2;
        int h0 = p >> 5;
        float a0 = 0.f, a1 = 0.f, c0 = 0.f, c1 = 0.f;
        const ushort* vb = src_bf + ((size_t)(b * NL + half * 128)) * ND + d0;
        const float* wl = &s_l[h0][half * 128];
        #pragma unroll 2
        for (int mm = 0; mm < 128; mm += 2) {
            float2 w2v = *(const float2*)(wl + mm);
            unsigned u0 = *(const unsigned*)(vb + (size_t)mm * ND);
            unsigned u1 = *(const unsigned*)(vb + (size_t)(mm + 1) * ND);
            a0 = fmaf(w2v.x, b2f_lo(u0), a0);
            a1 = fmaf(w2v.x, b2f_hi(u0), a1);
            c0 = fmaf(w2v.y, b2f_lo(u1), c0);
            c1 = fmaf(w2v.y, b2f_hi(u1), c1);
        }
        s_pv[half][d0] = a0 + c0;
        s_pv[half][d0 + 1] = a1 + c1;
    }
    __syncthreads();

    int d = t;
    float av = s_pv[0][d] + s_pv[1][d];
    float x0 = src[(size_t)row * ND + d] + av;
    float mu = block_sum8(x0, s_red) * (1.f / 512.f);
    float e0 = x0 - mu;
    float var = block_sum8(e0 * e0, s_red) * (1.f / 512.f);
    float rs = rsqrtf(var + 1e-5f);
    float o = e0 * rs * gamma1[d] + beta1[d];
    x1buf[(size_t)row * ND + d] = o;
    x1bf[(size_t)row * ND + d] = f2b(o);
}

// ---------------------------------------------------------------------------
// K3 (MFMA): hbf = bf16(leaky_relu(x1bf @ w1t^T + b1))
// ---------------------------------------------------------------------------
__global__ __launch_bounds__(256) void k3_mfma(const ushort* __restrict__ A,
                                               const ushort* __restrict__ Bt,
                                               const float* __restrict__ bias,
                                               ushort* __restrict__ C) {
    const int K = 512, N = 2048;
    int n0 = blockIdx.x * 64, m0 = blockIdx.y * 64;
    int t = threadIdx.x;
    int w = t >> 6, l = t & 63;
    __shared__ ushort As[64][40];
    __shared__ ushort Bs[64][40];
    f32x4 acc0 = {0.f, 0.f, 0.f, 0.f}, acc1 = acc0, acc2 = acc0, acc3 = acc0;
    int sr = t >> 2, sq = (t & 3) * 8;
    const ushort* Ap = A + (size_t)(m0 + sr) * K + sq;
    const ushort* Bp = Bt + (size_t)(n0 + sr) * K + sq;
    int lr = l & 15, lk = (l >> 4) * 8;
    for (int k0 = 0; k0 < K; k0 += 32) {
        uint4 av = *(const uint4*)(Ap + k0);
        uint4 bv = *(const uint4*)(Bp + k0);
        __syncthreads();
        *(uint4*)&As[sr][sq] = av;
        *(uint4*)&Bs[sr][sq] = bv;
        __syncthreads();
        bf16x8 af = *(const bf16x8*)&As[w * 16 + lr][lk];
        bf16x8 b0 = *(const bf16x8*)&Bs[0 * 16 + lr][lk];
        bf16x8 b1v = *(const bf16x8*)&Bs[1 * 16 + lr][lk];
        bf16x8 b2v = *(const bf16x8*)&Bs[2 * 16 + lr][lk];
        bf16x8 b3 = *(const bf16x8*)&Bs[3 * 16 + lr][lk];
        acc0 = __builtin_amdgcn_mfma_f32_16x16x32_bf16(af, b0, acc0, 0, 0, 0);
        acc1 = __builtin_amdgcn_mfma_f32_16x16x32_bf16(af, b1v, acc1, 0, 0, 0);
        acc2 = __builtin_amdgcn_mfma_f32_16x16x32_bf16(af, b2v, acc2, 0, 0, 0);
        acc3 = __builtin_amdgcn_mfma_f32_16x16x32_bf16(af, b3, acc3, 0, 0, 0);
    }
    int rbase = m0 + w * 16 + (l >> 4) * 4;
    #pragma unroll
    for (int e = 0; e < 4; ++e) {
        int row = rbase + e;
        float v;
        int col0 = n0 + lr;
        v = acc0[e] + bias[col0];
        C[(size_t)row * N + col0] = f2b(v >= 0.f ? v : 0.01f * v);
        v = acc1[e] + bias[col0 + 16];
        C[(size_t)row * N + col0 + 16] = f2b(v >= 0.f ? v : 0.01f * v);
        v = acc2[e] + bias[col0 + 32];
        C[(size_t)row * N + col0 + 32] = f2b(v >= 0.f ? v : 0.01f * v);
        v = acc3[e] + bias[col0 + 48];
        C[(size_t)row * N + col0 + 48] = f2b(v >= 0.f ? v : 0.01f * v);
    }
}

// ---------------------------------------------------------------------------
// K4 (MFMA): zpart[ks] = hbf[:, ks*512:+512] @ w2t^T chunk -> fp32
// ---------------------------------------------------------------------------
__global__ __launch_bounds__(256) void k4_mfma(const ushort* __restrict__ A,
                                               const ushort* __restrict__ Bt,
                                               float* __restrict__ Cp) {
    const int K = 2048, N = 512;
    int n0 = blockIdx.x * 64, m0 = blockIdx.y * 64;
    int ks = blockIdx.z;
    int t = threadIdx.x;
    int w = t >> 6, l = t & 63;
    __shared__ ushort As[64][40];
    __shared__ ushort Bs[64][40];
    f32x4 acc0 = {0.f, 0.f, 0.f, 0.f}, acc1 = acc0, acc2 = acc0, acc3 = acc0;
    int sr = t >> 2, sq = (t & 3) * 8;
    const ushort* Ap = A + (size_t)(m0 + sr) * K + ks * 512 + sq;
    const ushort* Bp = Bt + (size_t)(n0 + sr) * K + ks * 512 + sq;
    int lr = l & 15, lk = (l >> 4) * 8;
    for (int k0 = 0; k0 < 512; k0 += 32) {
        uint4 av = *(const uint4*)(Ap + k0);
        uint4 bv = *(const uint4*)(Bp + k0);
        __syncthreads();
        *(uint4*)&As[sr][sq] = av;
        *(uint4*)&Bs[sr][sq] = bv;
        __syncthreads();
        bf16x8 af = *(const bf16x8*)&As[w * 16 + lr][lk];
        bf16x8 b0 = *(const bf16x8*)&Bs[0 * 16 + lr][lk];
        bf16x8 b1v = *(const bf16x8*)&Bs[1 * 16 + lr][lk];
        bf16x8 b2v = *(const bf16x8*)&Bs[2 * 16 + lr][lk];
        bf16x8 b3 = *(const bf16x8*)&Bs[3 * 16 + lr][lk];
        acc0 = __builtin_amdgcn_mfma_f32_16x16x32_bf16(af, b0, acc0, 0, 0, 0);
        acc1 = __builtin_amdgcn_mfma_f32_16x16x32_bf16(af, b1v, acc1, 0, 0, 0);
        acc2 = __builtin_amdgcn_mfma_f32_16x16x32_bf16(af, b2v, acc2, 0, 0, 0);
        acc3 = __builtin_amdgcn_mfma_f32_16x16x32_bf16(af, b3, acc3, 0, 0, 0);
    }
    float* out = Cp + ((size_t)ks << 18);
    int rbase = m0 + w * 16 + (l >> 4) * 4;
    #pragma unroll
    for (int e = 0; e < 4; ++e) {
        int row = rbase + e;
        int col0 = n0 + lr;
        out[(size_t)row * N + col0] = acc0[e];
        out[(size_t)row * N + col0 + 16] = acc1[e];
        out[(size_t)row * N + col0 + 32] = acc2[e];
        out[(size_t)row * N + col0 + 48] = acc3[e];
    }
}

// ---------------------------------------------------------------------------
// K5: z = x1 + b2 + sum_ks zpart[ks]; out = LayerNorm2(z)
// ---------------------------------------------------------------------------
__global__ __launch_bounds__(256) void k5_final(const float* __restrict__ x1buf,
                                                const float* __restrict__ zpart,
                                                const float* __restrict__ b2,
                                                const float* __restrict__ gamma2,
                                                const float* __restrict__ beta2,
                                                float* __restrict__ out) {
    int row = blockIdx.x;
    int t = threadIdx.x;
    int d0 = t * 2;
    __shared__ float s_red[8];
    size_t off = (size_t)row * ND + d0;
    float2 v = *(const float2*)(x1buf + off);
    float2 bb = *(const float2*)(b2 + d0);
    float z0 = v.x + bb.x, z1 = v.y + bb.y;
    #pragma unroll
    for (int ks = 0; ks < 4; ++ks) {
        float2 p = *(const float2*)(zpart + ((size_t)ks << 18) + off);
        z0 += p.x;
        z1 += p.y;
    }
    float mu = block_sum4(z0 + z1, s_red) * (1.f / 512.f);
    float e0 = z0 - mu, e1 = z1 - mu;
    float var = block_sum4(e0 * e0 + e1 * e1, s_red) * (1.f / 512.f);
    float rs = rsqrtf(var + 1e-5f);
    float2 g = *(const float2*)(gamma2 + d0), be = *(const float2*)(beta2 + d0);
    *(float2*)(out + off) = make_float2(e0 * rs * g.x + be.x, e1 * rs * g.y + be.y);
}

// ---------------------------------------------------------------------------
extern "C" void kernel_launch(void* const* d_in, const int* in_sizes, int n_in,
                              void* d_out, int out_size, void* d_ws, size_t ws_size,
                              hipStream_t stream) {
    const float* src      = (const float*)d_in[0];
    const float* rel_diss = (const float*)d_in[1];
    const float* rel_dirs = (const float*)d_in[2];
    const float* rp_w     = (const float*)d_in[3];
    // d_in[4] = rp_b: constant over softmax axis -> cancels exactly; skipped
    const float* w1  = (const float*)d_in[5];
    const float* b1  = (const float*)d_in[6];
    const float* w2  = (const float*)d_in[7];
    const float* b2  = (const float*)d_in[8];
    const float* g1  = (const float*)d_in[9];
    const float* be1 = (const float*)d_in[10];
    const float* g2  = (const float*)d_in[11];
    const float* be2 = (const float*)d_in[12];
    float* out = (float*)d_out;

    float* ws = (float*)d_ws;
    float* x1buf = ws;                        // 262144 f
    float* zpart = x1buf + 262144;            // 1048576 f
    float* Wq    = zpart + 1048576;           // 2359296 f
    ushort* sbuf_bf = (ushort*)(Wq + WQROW * 512); // 1048576 u16
    ushort* w1t  = sbuf_bf + 1048576;             // 1048576 u16
    ushort* w2t  = w1t + 1048576;                 // 1048576 u16
    ushort* x1bf = w2t + 1048576;                 // 262144 u16
    ushort* hbf  = x1bf + 262144;                 // 1048576 u16
    ushort* src_bf = hbf + 1048576;               // 262144 u16

    k_pre<<<1600, 256, 0, stream>>>(src, rp_w, w1, w2, Wq, sbuf_bf, w1t, w2t, src_bf);
    k2_fused<<<512, 512, 0, stream>>>(src, src_bf, rel_diss, rel_dirs, Wq, sbuf_bf,
                                      g1, be1, x1buf, x1bf);
    k3_mfma<<<dim3(32, 8), 256, 0, stream>>>(x1bf, w1t, b1, hbf);
    k4_mfma<<<dim3(8, 8, 4), 256, 0, stream>>>(hbf, w2t, zpart);
    k5_final<<<512, 256, 0, stream>>>(x1buf, zpart, b2, g2, be2, out);
}

// Round 14
// 63.433 us; speedup vs baseline: 5.3009x; 1.0189x over previous
//
#include <hip/hip_runtime.h>

// Problem constants
#define NB 2
#define NL 256
#define ND 512
#define NH 8
#define NR 64
#define NS 9
#define NF 576
#define NHS 72      // NH*NS
#define WQROW 4608  // NR*NHS
#define RWIN 12     // rbf window: terms beyond 5.5*delta < 2e-7 -> negligible

typedef __attribute__((ext_vector_type(8))) short bf16x8;
typedef __attribute__((ext_vector_type(4))) float f32x4;

__device__ __forceinline__ ushort f2b(float f) {   // fp32 -> bf16 RNE
    union { float f; unsigned u; } c; c.f = f;
    unsigned u = c.u;
    return (ushort)((u + 0x7FFF + ((u >> 16) & 1)) >> 16);
}
__device__ __forceinline__ float b2f(ushort u) {   // bf16 -> fp32
    union { unsigned u; float f; } c; c.u = ((unsigned)u) << 16;
    return c.f;
}
__device__ __forceinline__ float b2f_lo(unsigned u) {
    union { unsigned u; float f; } c; c.u = u << 16;
    return c.f;
}
__device__ __forceinline__ float b2f_hi(unsigned u) {
    union { unsigned u; float f; } c; c.u = u & 0xffff0000u;
    return c.f;
}

__device__ __forceinline__ float block_sum8(float v, float* s_red) {
    #pragma unroll
    for (int off = 32; off; off >>= 1) v += __shfl_xor(v, off, 64);
    __syncthreads();
    if ((threadIdx.x & 63) == 0) s_red[threadIdx.x >> 6] = v;
    __syncthreads();
    return ((s_red[0] + s_red[1]) + (s_red[2] + s_red[3])) +
           ((s_red[4] + s_red[5]) + (s_red[6] + s_red[7]));
}

__device__ __forceinline__ float block_sum4(float v, float* s_red) {
    #pragma unroll
    for (int off = 32; off; off >>= 1) v += __shfl_xor(v, off, 64);
    __syncthreads();
    if ((threadIdx.x & 63) == 0) s_red[threadIdx.x >> 6] = v;
    __syncthreads();
    return s_red[0] + s_red[1] + s_red[2] + s_red[3];
}

// FMA 8 bf16 values packed in a uint4 against scalar rbf into acc[base..base+7]
#define FMA8(wv, base)                                      \
    acc[base + 0] = fmaf(b2f_lo(wv.x), rbf, acc[base + 0]); \
    acc[base + 1] = fmaf(b2f_hi(wv.x), rbf, acc[base + 1]); \
    acc[base + 2] = fmaf(b2f_lo(wv.y), rbf, acc[base + 2]); \
    acc[base + 3] = fmaf(b2f_hi(wv.y), rbf, acc[base + 3]); \
    acc[base + 4] = fmaf(b2f_lo(wv.z), rbf, acc[base + 4]); \
    acc[base + 5] = fmaf(b2f_hi(wv.z), rbf, acc[base + 5]); \
    acc[base + 6] = fmaf(b2f_lo(wv.w), rbf, acc[base + 6]); \
    acc[base + 7] = fmaf(b2f_hi(wv.w), rbf, acc[base + 7]);

// ---------------------------------------------------------------------------
// K_PRE: union of 5 independent pre-tasks, one dispatch (1600 blocks):
//   [0,256) t2b(w1)  [256,512) t2b(w2)  [512,1024) k1 (Wq -> bf16)
//   [1024,1536) k_qk (-> bf16 sbuf)  [1536,1600) src->bf16
// No inter-block dataflow inside this dispatch (CDNA4: fences/coop-sync cost
// ~60us in cross-XCD L2 coherence; dispatch boundaries are cheap).
// ---------------------------------------------------------------------------
__global__ __launch_bounds__(256, 4) void k_pre(const float* __restrict__ src,
                                                const float* __restrict__ rp_w,
                                                const float* __restrict__ w1,
                                                const float* __restrict__ w2,
                                                ushort* __restrict__ Wq,
                                                ushort* __restrict__ sbuf_bf,
                                                ushort* __restrict__ w1t,
                                                ushort* __restrict__ w2t,
                                                ushort* __restrict__ src_bf) {
    __shared__ __align__(16) char raw[26368];
    int bi = blockIdx.x;
    int t = threadIdx.x;

    if (bi < 512) {
        const float* in; ushort* out; int K, N, bx, by;
        if (bi < 256) { in = w1; out = w1t; K = 512; N = 2048; bx = bi & 31; by = bi >> 5; }
        else { int id = bi - 256; in = w2; out = w2t; K = 2048; N = 512; bx = id & 7; by = id >> 3; }
        float (*tile)[65] = (float(*)[65])raw;
        int n0 = bx * 64, k0 = by * 64;
        int r = t >> 4, c4 = (t & 15) * 4;
        #pragma unroll
        for (int i = 0; i < 4; ++i) {
            int kk = i * 16 + r;
            float4 v = *(const float4*)(in + (size_t)(k0 + kk) * N + n0 + c4);
            tile[kk][c4 + 0] = v.x;
            tile[kk][c4 + 1] = v.y;
            tile[kk][c4 + 2] = v.z;
            tile[kk][c4 + 3] = v.w;
        }
        __syncthreads();
        int rr = t >> 2, cq = (t & 3) * 16;
        ushort buf[16];
        #pragma unroll
        for (int j = 0; j < 16; ++j) buf[j] = f2b(tile[cq + j][rr]);
        ushort* op = out + (size_t)(n0 + rr) * K + k0 + cq;
        *(uint4*)(op) = *(uint4*)&buf[0];
        *(uint4*)(op + 8) = *(uint4*)&buf[8];
    } else if (bi < 1024) {
        int id = bi - 512;
        int rt = id & 63, h = id >> 6;
        float (*s_src)[64] = (float(*)[64])raw;
        float* s_B = (float*)(raw + 2048);
        int r0 = rt * 8;
        {
            int sr = t >> 5;
            int sc = (t & 31) * 2;
            *(float2*)&s_src[sr][sc] =
                *(const float2*)(src + (size_t)(r0 + sr) * ND + h * 64 + sc);
        }
        int ff = t & 63;
        int g  = t >> 6;
        int lr = t >> 2;
        int lq = t & 3;
        const float* bsrc = rp_w + h * 64;
        #pragma unroll 1
        for (int s = 0; s < NS; ++s) {
            __syncthreads();
            #pragma unroll
            for (int i = 0; i < 4; ++i) {
                int slot = i * 4 + lq;
                float4 v = *(const float4*)(bsrc + (size_t)(s * 64 + lr) * ND + slot * 4);
                int sw = slot ^ (lr & 7);
                *(float4*)&s_B[lr * 64 + sw * 4] = v;
            }
            __syncthreads();
            float a0 = 0.f, a1 = 0.f;
            #pragma unroll
            for (int d4 = 0; d4 < 16; ++d4) {
                int sw = d4 ^ (ff & 7);
                float4 bv = *(const float4*)&s_B[ff * 64 + sw * 4];
                float4 s0 = *(const float4*)&s_src[2 * g][d4 * 4];
                float4 s1 = *(const float4*)&s_src[2 * g + 1][d4 * 4];
                a0 = fmaf(bv.x, s0.x, a0);
                a0 = fmaf(bv.y, s0.y, a0);
                a0 = fmaf(bv.z, s0.z, a0);
                a0 = fmaf(bv.w, s0.w, a0);
                a1 = fmaf(bv.x, s1.x, a1);
                a1 = fmaf(bv.y, s1.y, a1);
                a1 = fmaf(bv.z, s1.z, a1);
                a1 = fmaf(bv.w, s1.w, a1);
            }
            Wq[(size_t)(r0 + 2 * g) * WQROW + ff * NHS + h * NS + s] = f2b(a0);
            Wq[(size_t)(r0 + 2 * g + 1) * WQROW + ff * NHS + h * NS + s] = f2b(a1);
        }
    } else if (bi < 1536) {
        int id = bi - 1024;
        int mt = id & 3, lt = (id >> 2) & 7, bh = id >> 5;
        int b = bh >> 3, h = bh & 7;
        int m0 = mt * 64, l0 = lt * 32;
        float (*s_A)[68] = (float(*)[68])raw;
        float (*s_B)[68] = (float(*)[68])(raw + 8704);
        #pragma unroll
        for (int i = 0; i < 2; ++i) {
            int idx = i * 256 + t;
            int row = idx >> 4, c4 = idx & 15;
            float4 v = *(const float4*)(src + (size_t)(b * NL + l0 + row) * ND + h * 64 + c4 * 4);
            *(float4*)&s_A[row][c4 * 4] = v;
        }
        {
            int mr = t >> 2, qd = t & 3;
            const float* kp = src + (size_t)(b * NL + m0 + mr) * ND + h * 64 + qd * 16;
            #pragma unroll
            for (int q = 0; q < 4; ++q) {
                float4 v = *(const float4*)(kp + q * 4);
                int d = qd * 16 + q * 4;
                s_B[d + 0][mr] = v.x;
                s_B[d + 1][mr] = v.y;
                s_B[d + 2][mr] = v.z;
                s_B[d + 3][mr] = v.w;
            }
        }
        __syncthreads();
        int tx = t & 15, ty = t >> 4;
        int ty2 = ty * 2;
        float acc[2][4] = {};
        #pragma unroll
        for (int d = 0; d < 64; ++d) {
            float a0 = s_A[ty2][d];
            float a1 = s_A[ty2 + 1][d];
            float4 bv = *(const float4*)&s_B[d][tx * 4];
            acc[0][0] = fmaf(a0, bv.x, acc[0][0]);
            acc[0][1] = fmaf(a0, bv.y, acc[0][1]);
            acc[0][2] = fmaf(a0, bv.z, acc[0][2]);
            acc[0][3] = fmaf(a0, bv.w, acc[0][3]);
            acc[1][0] = fmaf(a1, bv.x, acc[1][0]);
            acc[1][1] = fmaf(a1, bv.y, acc[1][1]);
            acc[1][2] = fmaf(a1, bv.z, acc[1][2]);
            acc[1][3] = fmaf(a1, bv.w, acc[1][3]);
        }
        #pragma unroll
        for (int i = 0; i < 2; ++i) {
            size_t off = ((size_t)bh * NL + l0 + ty2 + i) * NL + m0 + tx * 4;
            unsigned p0 = (unsigned)f2b(acc[i][0] * 0.125f) |
                          ((unsigned)f2b(acc[i][1] * 0.125f) << 16);
            unsigned p1 = (unsigned)f2b(acc[i][2] * 0.125f) |
                          ((unsigned)f2b(acc[i][3] * 0.125f) << 16);
            uint2 pk; pk.x = p0; pk.y = p1;
            *(uint2*)(sbuf_bf + off) = pk;
        }
    } else {
        int id = bi - 1536;
        size_t base = (size_t)id * 4096 + (size_t)t * 16;
        const float4* ip = (const float4*)(src + base);
        float4 v0 = ip[0], v1 = ip[1], v2 = ip[2], v3 = ip[3];
        ushort o[16];
        o[0] = f2b(v0.x); o[1] = f2b(v0.y); o[2] = f2b(v0.z); o[3] = f2b(v0.w);
        o[4] = f2b(v1.x); o[5] = f2b(v1.y); o[6] = f2b(v1.z); o[7] = f2b(v1.w);
        o[8] = f2b(v2.x); o[9] = f2b(v2.y); o[10] = f2b(v2.z); o[11] = f2b(v2.w);
        o[12] = f2b(v3.x); o[13] = f2b(v3.y); o[14] = f2b(v3.z); o[15] = f2b(v3.w);
        *(uint4*)(src_bf + base) = *(uint4*)&o[0];
        *(uint4*)(src_bf + base + 8) = *(uint4*)&o[8];
    }
}

// ---------------------------------------------------------------------------
// K2_FUSED: per row (512 threads): rp logits (bf16 Wq in LDS, 5 LDS reads +
// VALU unpack per window step) + base QK (bf16 sbuf) + softmax + PV (bf16 V,
// fp32 accum) + residual(fp32 src) + LN1.
// ---------------------------------------------------------------------------
__global__ __launch_bounds__(512, 4) void k2_fused(const float* __restrict__ src,
                                                   const ushort* __restrict__ src_bf,
                                                   const float* __restrict__ rel_diss,
                                                   const float* __restrict__ rel_dirs,
                                                   const ushort* __restrict__ Wq,
                                                   const ushort* __restrict__ sbuf_bf,
                                                   const float* __restrict__ gamma1,
                                                   const float* __restrict__ beta1,
                                                   float* __restrict__ x1buf,
                                                   ushort* __restrict__ x1bf) {
    int row = blockIdx.x;
    int b = row >> 8;
    int l = row & 255;
    int t = threadIdx.x;
    int m = t & 255;
    int hg = t >> 8;
    __shared__ ushort s_wq[2][64][40];   // 10240 B: [hg][r][36+4 pad], 80B rows
    __shared__ float s_l[NH][NL];        // 8192 B
    __shared__ float s_pv[2][ND];        // 4096 B
    __shared__ float s_red[8];

    // --- stage bf16 Wq row into split-padded LDS layout ---
    const ushort* wrow = Wq + (size_t)row * WQROW;
    #pragma unroll
    for (int i = 0; i < 9; ++i) {
        int flat = i * 512 + t;              // r*72 + c
        int r = flat / 72, c = flat - 72 * r;
        int hgd = (c >= 36) ? 1 : 0;
        s_wq[hgd][r][c - hgd * 36] = wrow[flat];
    }
    float dist = rel_diss[(size_t)row * NL + m];
    const float* dirp = rel_dirs + ((size_t)row * NL + m) * 3;
    float x = dirp[0], y = dirp[1], z = dirp[2];
    float tcl = fminf(fmaxf(dist * 0.1f, 0.f), 1.f);
    float env = 0.5f * (__cosf(3.14159265358979f * tcl) + 1.f);
    int rc = (int)floorf(dist * 6.3f + 0.5f);
    int rlo = min(max(rc - 6, 0), NR - RWIN);
    float sph[NS];
    sph[0] = 0.28209479177387814f * env;
    sph[1] = 0.4886025119029199f * y * env;
    sph[2] = 0.4886025119029199f * z * env;
    sph[3] = 0.4886025119029199f * x * env;
    sph[4] = 1.0925484305920792f * x * y * env;
    sph[5] = 1.0925484305920792f * y * z * env;
    sph[6] = 0.31539156525252005f * (3.f * z * z - 1.f) * env;
    sph[7] = 1.0925484305920792f * x * z * env;
    sph[8] = 0.5462742152960396f * (x * x - y * y) * env;
    __syncthreads();

    float acc[36];
    #pragma unroll
    for (int i = 0; i < 36; ++i) acc[i] = 0.f;
    #pragma unroll 4
    for (int rw = 0; rw < RWIN; ++rw) {
        int r = rlo + rw;
        float df = dist - r * (10.f / 63.f);
        float rbf = __expf(-df * df * 20.48f);
        const ushort* wp = &s_wq[hg][r][0];
        uint4 wa = *(const uint4*)(wp);        // hs 0..7
        uint4 wb = *(const uint4*)(wp + 8);    // hs 8..15
        uint4 wc = *(const uint4*)(wp + 16);   // hs 16..23
        uint4 wd = *(const uint4*)(wp + 24);   // hs 24..31
        uint2 we = *(const uint2*)(wp + 32);   // hs 32..35
        FMA8(wa, 0)
        FMA8(wb, 8)
        FMA8(wc, 16)
        FMA8(wd, 24)
        acc[32] = fmaf(b2f_lo(we.x), rbf, acc[32]);
        acc[33] = fmaf(b2f_hi(we.x), rbf, acc[33]);
        acc[34] = fmaf(b2f_lo(we.y), rbf, acc[34]);
        acc[35] = fmaf(b2f_hi(we.y), rbf, acc[35]);
    }
    const ushort* sb = sbuf_bf + (((size_t)(b * NH + hg * 4) * NL) + l) * NL + m;
    #pragma unroll
    for (int hh = 0; hh < 4; ++hh) {
        float sc = 0.f;
        #pragma unroll
        for (int s = 0; s < NS; ++s) sc = fmaf(sph[s], acc[hh * NS + s], sc);
        s_l[hg * 4 + hh][m] = sc + b2f(sb[(size_t)hh * NL * NL]);
    }
    __syncthreads();

    int wv = t >> 6, lane = t & 63;
    {
        float v0 = s_l[wv][lane], v1 = s_l[wv][lane + 64];
        float v2 = s_l[wv][lane + 128], v3 = s_l[wv][lane + 192];
        float mx = fmaxf(fmaxf(v0, v1), fmaxf(v2, v3));
        #pragma unroll
        for (int off = 32; off; off >>= 1) mx = fmaxf(mx, __shfl_xor(mx, off, 64));
        float p0 = __expf(v0 - mx), p1 = __expf(v1 - mx);
        float p2 = __expf(v2 - mx), p3 = __expf(v3 - mx);
        float sm = p0 + p1 + p2 + p3;
        #pragma unroll
        for (int off = 32; off; off >>= 1) sm += __shfl_xor(sm, off, 64);
        float inv = 1.f / sm;
        s_l[wv][lane] = p0 * inv;
        s_l[wv][lane + 64] = p1 * inv;
        s_l[wv][lane + 128] = p2 * inv;
        s_l[wv][lane + 192] = p3 * inv;
    }
    __syncthreads();

    // --- PV: thread = (d-pair p, m-half), V read as bf16 pairs ---
    {
        int p = t & 255, half = t >> 8;
        int d0 = p * 2;
        int h0 = p >> 5;
        float a0 = 0.f, a1 = 0.f, c0 = 0.f, c1 = 0.f;
        const ushort* vb = src_bf + ((size_t)(b * NL + half * 128)) * ND + d0;
        const float* wl = &s_l[h0][half * 128];
        #pragma unroll 2
        for (int mm = 0; mm < 128; mm += 2) {
            float2 w2v = *(const float2*)(wl + mm);
            unsigned u0 = *(const unsigned*)(vb + (size_t)mm * ND);
            unsigned u1 = *(const unsigned*)(vb + (size_t)(mm + 1) * ND);
            a0 = fmaf(w2v.x, b2f_lo(u0), a0);
            a1 = fmaf(w2v.x, b2f_hi(u0), a1);
            c0 = fmaf(w2v.y, b2f_lo(u1), c0);
            c1 = fmaf(w2v.y, b2f_hi(u1), c1);
        }
        s_pv[half][d0] = a0 + c0;
        s_pv[half][d0 + 1] = a1 + c1;
    }
    __syncthreads();

    int d = t;
    float av = s_pv[0][d] + s_pv[1][d];
    float x0 = src[(size_t)row * ND + d] + av;
    float mu = block_sum8(x0, s_red) * (1.f / 512.f);
    float e0 = x0 - mu;
    float var = block_sum8(e0 * e0, s_red) * (1.f / 512.f);
    float rs = rsqrtf(var + 1e-5f);
    float o = e0 * rs * gamma1[d] + beta1[d];
    x1buf[(size_t)row * ND + d] = o;
    x1bf[(size_t)row * ND + d] = f2b(o);
}

// ---------------------------------------------------------------------------
// K3 (MFMA): hbf = bf16(leaky_relu(x1bf @ w1t^T + b1))
// ---------------------------------------------------------------------------
__global__ __launch_bounds__(256) void k3_mfma(const ushort* __restrict__ A,
                                               const ushort* __restrict__ Bt,
                                               const float* __restrict__ bias,
                                               ushort* __restrict__ C) {
    const int K = 512, N = 2048;
    int n0 = blockIdx.x * 64, m0 = blockIdx.y * 64;
    int t = threadIdx.x;
    int w = t >> 6, l = t & 63;
    __shared__ ushort As[64][40];
    __shared__ ushort Bs[64][40];
    f32x4 acc0 = {0.f, 0.f, 0.f, 0.f}, acc1 = acc0, acc2 = acc0, acc3 = acc0;
    int sr = t >> 2, sq = (t & 3) * 8;
    const ushort* Ap = A + (size_t)(m0 + sr) * K + sq;
    const ushort* Bp = Bt + (size_t)(n0 + sr) * K + sq;
    int lr = l & 15, lk = (l >> 4) * 8;
    for (int k0 = 0; k0 < K; k0 += 32) {
        uint4 av = *(const uint4*)(Ap + k0);
        uint4 bv = *(const uint4*)(Bp + k0);
        __syncthreads();
        *(uint4*)&As[sr][sq] = av;
        *(uint4*)&Bs[sr][sq] = bv;
        __syncthreads();
        bf16x8 af = *(const bf16x8*)&As[w * 16 + lr][lk];
        bf16x8 b0 = *(const bf16x8*)&Bs[0 * 16 + lr][lk];
        bf16x8 b1v = *(const bf16x8*)&Bs[1 * 16 + lr][lk];
        bf16x8 b2v = *(const bf16x8*)&Bs[2 * 16 + lr][lk];
        bf16x8 b3 = *(const bf16x8*)&Bs[3 * 16 + lr][lk];
        acc0 = __builtin_amdgcn_mfma_f32_16x16x32_bf16(af, b0, acc0, 0, 0, 0);
        acc1 = __builtin_amdgcn_mfma_f32_16x16x32_bf16(af, b1v, acc1, 0, 0, 0);
        acc2 = __builtin_amdgcn_mfma_f32_16x16x32_bf16(af, b2v, acc2, 0, 0, 0);
        acc3 = __builtin_amdgcn_mfma_f32_16x16x32_bf16(af, b3, acc3, 0, 0, 0);
    }
    int rbase = m0 + w * 16 + (l >> 4) * 4;
    #pragma unroll
    for (int e = 0; e < 4; ++e) {
        int row = rbase + e;
        float v;
        int col0 = n0 + lr;
        v = acc0[e] + bias[col0];
        C[(size_t)row * N + col0] = f2b(v >= 0.f ? v : 0.01f * v);
        v = acc1[e] + bias[col0 + 16];
        C[(size_t)row * N + col0 + 16] = f2b(v >= 0.f ? v : 0.01f * v);
        v = acc2[e] + bias[col0 + 32];
        C[(size_t)row * N + col0 + 32] = f2b(v >= 0.f ? v : 0.01f * v);
        v = acc3[e] + bias[col0 + 48];
        C[(size_t)row * N + col0 + 48] = f2b(v >= 0.f ? v : 0.01f * v);
    }
}

// ---------------------------------------------------------------------------
// K4 (MFMA): zpart[ks] = hbf[:, ks*512:+512] @ w2t^T chunk -> fp32
// ---------------------------------------------------------------------------
__global__ __launch_bounds__(256) void k4_mfma(const ushort* __restrict__ A,
                                               const ushort* __restrict__ Bt,
                                               float* __restrict__ Cp) {
    const int K = 2048, N = 512;
    int n0 = blockIdx.x * 64, m0 = blockIdx.y * 64;
    int ks = blockIdx.z;
    int t = threadIdx.x;
    int w = t >> 6, l = t & 63;
    __shared__ ushort As[64][40];
    __shared__ ushort Bs[64][40];
    f32x4 acc0 = {0.f, 0.f, 0.f, 0.f}, acc1 = acc0, acc2 = acc0, acc3 = acc0;
    int sr = t >> 2, sq = (t & 3) * 8;
    const ushort* Ap = A + (size_t)(m0 + sr) * K + ks * 512 + sq;
    const ushort* Bp = Bt + (size_t)(n0 + sr) * K + ks * 512 + sq;
    int lr = l & 15, lk = (l >> 4) * 8;
    for (int k0 = 0; k0 < 512; k0 += 32) {
        uint4 av = *(const uint4*)(Ap + k0);
        uint4 bv = *(const uint4*)(Bp + k0);
        __syncthreads();
        *(uint4*)&As[sr][sq] = av;
        *(uint4*)&Bs[sr][sq] = bv;
        __syncthreads();
        bf16x8 af = *(const bf16x8*)&As[w * 16 + lr][lk];
        bf16x8 b0 = *(const bf16x8*)&Bs[0 * 16 + lr][lk];
        bf16x8 b1v = *(const bf16x8*)&Bs[1 * 16 + lr][lk];
        bf16x8 b2v = *(const bf16x8*)&Bs[2 * 16 + lr][lk];
        bf16x8 b3 = *(const bf16x8*)&Bs[3 * 16 + lr][lk];
        acc0 = __builtin_amdgcn_mfma_f32_16x16x32_bf16(af, b0, acc0, 0, 0, 0);
        acc1 = __builtin_amdgcn_mfma_f32_16x16x32_bf16(af, b1v, acc1, 0, 0, 0);
        acc2 = __builtin_amdgcn_mfma_f32_16x16x32_bf16(af, b2v, acc2, 0, 0, 0);
        acc3 = __builtin_amdgcn_mfma_f32_16x16x32_bf16(af, b3, acc3, 0, 0, 0);
    }
    float* out = Cp + ((size_t)ks << 18);
    int rbase = m0 + w * 16 + (l >> 4) * 4;
    #pragma unroll
    for (int e = 0; e < 4; ++e) {
        int row = rbase + e;
        int col0 = n0 + lr;
        out[(size_t)row * N + col0] = acc0[e];
        out[(size_t)row * N + col0 + 16] = acc1[e];
        out[(size_t)row * N + col0 + 32] = acc2[e];
        out[(size_t)row * N + col0 + 48] = acc3[e];
    }
}

// ---------------------------------------------------------------------------
// K5: z = x1 + b2 + sum_ks zpart[ks]; out = LayerNorm2(z)
// ---------------------------------------------------------------------------
__global__ __launch_bounds__(256) void k5_final(const float* __restrict__ x1buf,
                                                const float* __restrict__ zpart,
                                                const float* __restrict__ b2,
                                                const float* __restrict__ gamma2,
                                                const float* __restrict__ beta2,
                                                float* __restrict__ out) {
    int row = blockIdx.x;
    int t = threadIdx.x;
    int d0 = t * 2;
    __shared__ float s_red[8];
    size_t off = (size_t)row * ND + d0;
    float2 v = *(const float2*)(x1buf + off);
    float2 bb = *(const float2*)(b2 + d0);
    float z0 = v.x + bb.x, z1 = v.y + bb.y;
    #pragma unroll
    for (int ks = 0; ks < 4; ++ks) {
        float2 p = *(const float2*)(zpart + ((size_t)ks << 18) + off);
        z0 += p.x;
        z1 += p.y;
    }
    float mu = block_sum4(z0 + z1, s_red) * (1.f / 512.f);
    float e0 = z0 - mu, e1 = z1 - mu;
    float var = block_sum4(e0 * e0 + e1 * e1, s_red) * (1.f / 512.f);
    float rs = rsqrtf(var + 1e-5f);
    float2 g = *(const float2*)(gamma2 + d0), be = *(const float2*)(beta2 + d0);
    *(float2*)(out + off) = make_float2(e0 * rs * g.x + be.x, e1 * rs * g.y + be.y);
}

// ---------------------------------------------------------------------------
extern "C" void kernel_launch(void* const* d_in, const int* in_sizes, int n_in,
                              void* d_out, int out_size, void* d_ws, size_t ws_size,
                              hipStream_t stream) {
    const float* src      = (const float*)d_in[0];
    const float* rel_diss = (const float*)d_in[1];
    const float* rel_dirs = (const float*)d_in[2];
    const float* rp_w     = (const float*)d_in[3];
    // d_in[4] = rp_b: constant over softmax axis -> cancels exactly; skipped
    const float* w1  = (const float*)d_in[5];
    const float* b1  = (const float*)d_in[6];
    const float* w2  = (const float*)d_in[7];
    const float* b2  = (const float*)d_in[8];
    const float* g1  = (const float*)d_in[9];
    const float* be1 = (const float*)d_in[10];
    const float* g2  = (const float*)d_in[11];
    const float* be2 = (const float*)d_in[12];
    float* out = (float*)d_out;

    float* ws = (float*)d_ws;
    float* x1buf = ws;                            // 262144 f
    float* zpart = x1buf + 262144;                // 1048576 f
    ushort* Wq   = (ushort*)(zpart + 1048576);    // 2359296 u16 (bf16)
    ushort* sbuf_bf = Wq + 2359296;               // 1048576 u16
    ushort* w1t  = sbuf_bf + 1048576;             // 1048576 u16
    ushort* w2t  = w1t + 1048576;                 // 1048576 u16
    ushort* x1bf = w2t + 1048576;                 // 262144 u16
    ushort* hbf  = x1bf + 262144;                 // 1048576 u16
    ushort* src_bf = hbf + 1048576;               // 262144 u16

    k_pre<<<1600, 256, 0, stream>>>(src, rp_w, w1, w2, Wq, sbuf_bf, w1t, w2t, src_bf);
    k2_fused<<<512, 512, 0, stream>>>(src, src_bf, rel_diss, rel_dirs, Wq, sbuf_bf,
                                      g1, be1, x1buf, x1bf);
    k3_mfma<<<dim3(32, 8), 256, 0, stream>>>(x1bf, w1t, b1, hbf);
    k4_mfma<<<dim3(8, 8, 4), 256, 0, stream>>>(hbf, w2t, zpart);
    k5_final<<<512, 256, 0, stream>>>(x1buf, zpart, b2, g2, be2, out);
}

// Round 15
// 60.596 us; speedup vs baseline: 5.5492x; 1.0468x over previous
//
#include <hip/hip_runtime.h>

// Problem constants
#define NB 2
#define NL 256
#define ND 512
#define NH 8
#define NR 64
#define NS 9
#define NF 576
#define NHS 72      // NH*NS
#define WQROW 4608  // NR*NHS
#define RWIN 12     // rbf window: terms beyond 5.5*delta < 2e-7 -> negligible

typedef __attribute__((ext_vector_type(8))) short bf16x8;
typedef __attribute__((ext_vector_type(4))) float f32x4;

__device__ __forceinline__ ushort f2b(float f) {   // fp32 -> bf16 RNE
    union { float f; unsigned u; } c; c.f = f;
    unsigned u = c.u;
    return (ushort)((u + 0x7FFF + ((u >> 16) & 1)) >> 16);
}
__device__ __forceinline__ float b2f(ushort u) {   // bf16 -> fp32
    union { unsigned u; float f; } c; c.u = ((unsigned)u) << 16;
    return c.f;
}
__device__ __forceinline__ float b2f_lo(unsigned u) {
    union { unsigned u; float f; } c; c.u = u << 16;
    return c.f;
}
__device__ __forceinline__ float b2f_hi(unsigned u) {
    union { unsigned u; float f; } c; c.u = u & 0xffff0000u;
    return c.f;
}

__device__ __forceinline__ float block_sum8(float v, float* s_red) {
    #pragma unroll
    for (int off = 32; off; off >>= 1) v += __shfl_xor(v, off, 64);
    __syncthreads();
    if ((threadIdx.x & 63) == 0) s_red[threadIdx.x >> 6] = v;
    __syncthreads();
    return ((s_red[0] + s_red[1]) + (s_red[2] + s_red[3])) +
           ((s_red[4] + s_red[5]) + (s_red[6] + s_red[7]));
}

__device__ __forceinline__ float block_sum4(float v, float* s_red) {
    #pragma unroll
    for (int off = 32; off; off >>= 1) v += __shfl_xor(v, off, 64);
    __syncthreads();
    if ((threadIdx.x & 63) == 0) s_red[threadIdx.x >> 6] = v;
    __syncthreads();
    return s_red[0] + s_red[1] + s_red[2] + s_red[3];
}

// FMA 8 bf16 values packed in a uint4 against scalar rbf into acc[base..base+7]
#define FMA8(wv, base)                                      \
    acc[base + 0] = fmaf(b2f_lo(wv.x), rbf, acc[base + 0]); \
    acc[base + 1] = fmaf(b2f_hi(wv.x), rbf, acc[base + 1]); \
    acc[base + 2] = fmaf(b2f_lo(wv.y), rbf, acc[base + 2]); \
    acc[base + 3] = fmaf(b2f_hi(wv.y), rbf, acc[base + 3]); \
    acc[base + 4] = fmaf(b2f_lo(wv.z), rbf, acc[base + 4]); \
    acc[base + 5] = fmaf(b2f_hi(wv.z), rbf, acc[base + 5]); \
    acc[base + 6] = fmaf(b2f_lo(wv.w), rbf, acc[base + 6]); \
    acc[base + 7] = fmaf(b2f_hi(wv.w), rbf, acc[base + 7]);

// ---------------------------------------------------------------------------
// K_PRE: union of 5 independent pre-tasks, one dispatch (1600 blocks):
//   [0,256) t2b(w1)  [256,512) t2b(w2)  [512,1024) k1 (bf16 B-stage, Wq bf16)
//   [1024,1536) k_qk (-> bf16 sbuf)  [1536,1600) src->bf16
// No inter-block dataflow inside this dispatch (CDNA4: fences/coop-sync cost
// ~60us in cross-XCD L2 coherence; dispatch boundaries are cheap).
// ---------------------------------------------------------------------------
__global__ __launch_bounds__(256, 4) void k_pre(const float* __restrict__ src,
                                                const float* __restrict__ rp_w,
                                                const float* __restrict__ w1,
                                                const float* __restrict__ w2,
                                                ushort* __restrict__ Wq,
                                                ushort* __restrict__ sbuf_bf,
                                                ushort* __restrict__ w1t,
                                                ushort* __restrict__ w2t,
                                                ushort* __restrict__ src_bf) {
    __shared__ __align__(16) char raw[26368];
    int bi = blockIdx.x;
    int t = threadIdx.x;

    if (bi < 512) {
        const float* in; ushort* out; int K, N, bx, by;
        if (bi < 256) { in = w1; out = w1t; K = 512; N = 2048; bx = bi & 31; by = bi >> 5; }
        else { int id = bi - 256; in = w2; out = w2t; K = 2048; N = 512; bx = id & 7; by = id >> 3; }
        float (*tile)[65] = (float(*)[65])raw;
        int n0 = bx * 64, k0 = by * 64;
        int r = t >> 4, c4 = (t & 15) * 4;
        #pragma unroll
        for (int i = 0; i < 4; ++i) {
            int kk = i * 16 + r;
            float4 v = *(const float4*)(in + (size_t)(k0 + kk) * N + n0 + c4);
            tile[kk][c4 + 0] = v.x;
            tile[kk][c4 + 1] = v.y;
            tile[kk][c4 + 2] = v.z;
            tile[kk][c4 + 3] = v.w;
        }
        __syncthreads();
        int rr = t >> 2, cq = (t & 3) * 16;
        ushort buf[16];
        #pragma unroll
        for (int j = 0; j < 16; ++j) buf[j] = f2b(tile[cq + j][rr]);
        ushort* op = out + (size_t)(n0 + rr) * K + k0 + cq;
        *(uint4*)(op) = *(uint4*)&buf[0];
        *(uint4*)(op + 8) = *(uint4*)&buf[8];
    } else if (bi < 1024) {
        // ---- k1: Wq (bf16 rp_w staging in padded LDS, fp32 accum) ----
        int id = bi - 512;
        int rt = id & 63, h = id >> 6;
        float (*s_src)[64] = (float(*)[64])raw;            // 2048 B
        ushort (*s_Bh)[68] = (ushort(*)[68])(raw + 2048);  // 8704 B
        int r0 = rt * 8;
        {
            int sr = t >> 5;
            int sc = (t & 31) * 2;
            *(float2*)&s_src[sr][sc] =
                *(const float2*)(src + (size_t)(r0 + sr) * ND + h * 64 + sc);
        }
        int ff = t & 63;
        int g  = t >> 6;
        int lr = t >> 2;
        int lq = t & 3;
        const float* bsrc = rp_w + h * 64;
        #pragma unroll 1
        for (int s = 0; s < NS; ++s) {
            __syncthreads();
            #pragma unroll
            for (int i = 0; i < 4; ++i) {
                int slot = i * 4 + lq;                 // 0..15
                float4 v = *(const float4*)(bsrc + (size_t)(s * 64 + lr) * ND + slot * 4);
                uint2 pk;
                pk.x = (unsigned)f2b(v.x) | ((unsigned)f2b(v.y) << 16);
                pk.y = (unsigned)f2b(v.z) | ((unsigned)f2b(v.w) << 16);
                *(uint2*)&s_Bh[lr][slot * 4] = pk;
            }
            __syncthreads();
            float a0 = 0.f, a1 = 0.f;
            #pragma unroll
            for (int d4 = 0; d4 < 16; ++d4) {
                uint2 bv = *(const uint2*)&s_Bh[ff][d4 * 4];
                float4 s0 = *(const float4*)&s_src[2 * g][d4 * 4];
                float4 s1 = *(const float4*)&s_src[2 * g + 1][d4 * 4];
                float e0 = b2f_lo(bv.x), e1 = b2f_hi(bv.x);
                float e2 = b2f_lo(bv.y), e3 = b2f_hi(bv.y);
                a0 = fmaf(e0, s0.x, a0);
                a0 = fmaf(e1, s0.y, a0);
                a0 = fmaf(e2, s0.z, a0);
                a0 = fmaf(e3, s0.w, a0);
                a1 = fmaf(e0, s1.x, a1);
                a1 = fmaf(e1, s1.y, a1);
                a1 = fmaf(e2, s1.z, a1);
                a1 = fmaf(e3, s1.w, a1);
            }
            Wq[(size_t)(r0 + 2 * g) * WQROW + ff * NHS + h * NS + s] = f2b(a0);
            Wq[(size_t)(r0 + 2 * g + 1) * WQROW + ff * NHS + h * NS + s] = f2b(a1);
        }
    } else if (bi < 1536) {
        int id = bi - 1024;
        int mt = id & 3, lt = (id >> 2) & 7, bh = id >> 5;
        int b = bh >> 3, h = bh & 7;
        int m0 = mt * 64, l0 = lt * 32;
        float (*s_A)[68] = (float(*)[68])raw;
        float (*s_B)[68] = (float(*)[68])(raw + 8704);
        #pragma unroll
        for (int i = 0; i < 2; ++i) {
            int idx = i * 256 + t;
            int row = idx >> 4, c4 = idx & 15;
            float4 v = *(const float4*)(src + (size_t)(b * NL + l0 + row) * ND + h * 64 + c4 * 4);
            *(float4*)&s_A[row][c4 * 4] = v;
        }
        {
            int mr = t >> 2, qd = t & 3;
            const float* kp = src + (size_t)(b * NL + m0 + mr) * ND + h * 64 + qd * 16;
            #pragma unroll
            for (int q = 0; q < 4; ++q) {
                float4 v = *(const float4*)(kp + q * 4);
                int d = qd * 16 + q * 4;
                s_B[d + 0][mr] = v.x;
                s_B[d + 1][mr] = v.y;
                s_B[d + 2][mr] = v.z;
                s_B[d + 3][mr] = v.w;
            }
        }
        __syncthreads();
        int tx = t & 15, ty = t >> 4;
        int ty2 = ty * 2;
        float acc[2][4] = {};
        #pragma unroll
        for (int d = 0; d < 64; ++d) {
            float a0 = s_A[ty2][d];
            float a1 = s_A[ty2 + 1][d];
            float4 bv = *(const float4*)&s_B[d][tx * 4];
            acc[0][0] = fmaf(a0, bv.x, acc[0][0]);
            acc[0][1] = fmaf(a0, bv.y, acc[0][1]);
            acc[0][2] = fmaf(a0, bv.z, acc[0][2]);
            acc[0][3] = fmaf(a0, bv.w, acc[0][3]);
            acc[1][0] = fmaf(a1, bv.x, acc[1][0]);
            acc[1][1] = fmaf(a1, bv.y, acc[1][1]);
            acc[1][2] = fmaf(a1, bv.z, acc[1][2]);
            acc[1][3] = fmaf(a1, bv.w, acc[1][3]);
        }
        #pragma unroll
        for (int i = 0; i < 2; ++i) {
            size_t off = ((size_t)bh * NL + l0 + ty2 + i) * NL + m0 + tx * 4;
            unsigned p0 = (unsigned)f2b(acc[i][0] * 0.125f) |
                          ((unsigned)f2b(acc[i][1] * 0.125f) << 16);
            unsigned p1 = (unsigned)f2b(acc[i][2] * 0.125f) |
                          ((unsigned)f2b(acc[i][3] * 0.125f) << 16);
            uint2 pk; pk.x = p0; pk.y = p1;
            *(uint2*)(sbuf_bf + off) = pk;
        }
    } else {
        int id = bi - 1536;
        size_t base = (size_t)id * 4096 + (size_t)t * 16;
        const float4* ip = (const float4*)(src + base);
        float4 v0 = ip[0], v1 = ip[1], v2 = ip[2], v3 = ip[3];
        ushort o[16];
        o[0] = f2b(v0.x); o[1] = f2b(v0.y); o[2] = f2b(v0.z); o[3] = f2b(v0.w);
        o[4] = f2b(v1.x); o[5] = f2b(v1.y); o[6] = f2b(v1.z); o[7] = f2b(v1.w);
        o[8] = f2b(v2.x); o[9] = f2b(v2.y); o[10] = f2b(v2.z); o[11] = f2b(v2.w);
        o[12] = f2b(v3.x); o[13] = f2b(v3.y); o[14] = f2b(v3.z); o[15] = f2b(v3.w);
        *(uint4*)(src_bf + base) = *(uint4*)&o[0];
        *(uint4*)(src_bf + base + 8) = *(uint4*)&o[8];
    }
}

// ---------------------------------------------------------------------------
// K2_FUSED: per row (512 threads): rp logits (bf16 Wq) + base QK (bf16 sbuf)
// + softmax + PV (d-quad vectorized: uint2 = 4 dims/load, 4 m-quarters)
// + residual(fp32 src) + LN1.
// ---------------------------------------------------------------------------
__global__ __launch_bounds__(512, 4) void k2_fused(const float* __restrict__ src,
                                                   const ushort* __restrict__ src_bf,
                                                   const float* __restrict__ rel_diss,
                                                   const float* __restrict__ rel_dirs,
                                                   const ushort* __restrict__ Wq,
                                                   const ushort* __restrict__ sbuf_bf,
                                                   const float* __restrict__ gamma1,
                                                   const float* __restrict__ beta1,
                                                   float* __restrict__ x1buf,
                                                   ushort* __restrict__ x1bf) {
    int row = blockIdx.x;
    int b = row >> 8;
    int l = row & 255;
    int t = threadIdx.x;
    int m = t & 255;
    int hg = t >> 8;
    __shared__ ushort s_wq[2][64][40];   // 10240 B
    __shared__ float s_l[NH][NL];        // 8192 B
    __shared__ float s_pv[4][ND];        // 8192 B
    __shared__ float s_red[8];

    const ushort* wrow = Wq + (size_t)row * WQROW;
    #pragma unroll
    for (int i = 0; i < 9; ++i) {
        int flat = i * 512 + t;              // r*72 + c
        int r = flat / 72, c = flat - 72 * r;
        int hgd = (c >= 36) ? 1 : 0;
        s_wq[hgd][r][c - hgd * 36] = wrow[flat];
    }
    float dist = rel_diss[(size_t)row * NL + m];
    const float* dirp = rel_dirs + ((size_t)row * NL + m) * 3;
    float x = dirp[0], y = dirp[1], z = dirp[2];
    float tcl = fminf(fmaxf(dist * 0.1f, 0.f), 1.f);
    float env = 0.5f * (__cosf(3.14159265358979f * tcl) + 1.f);
    int rc = (int)floorf(dist * 6.3f + 0.5f);
    int rlo = min(max(rc - 6, 0), NR - RWIN);
    float sph[NS];
    sph[0] = 0.28209479177387814f * env;
    sph[1] = 0.4886025119029199f * y * env;
    sph[2] = 0.4886025119029199f * z * env;
    sph[3] = 0.4886025119029199f * x * env;
    sph[4] = 1.0925484305920792f * x * y * env;
    sph[5] = 1.0925484305920792f * y * z * env;
    sph[6] = 0.31539156525252005f * (3.f * z * z - 1.f) * env;
    sph[7] = 1.0925484305920792f * x * z * env;
    sph[8] = 0.5462742152960396f * (x * x - y * y) * env;
    __syncthreads();

    float acc[36];
    #pragma unroll
    for (int i = 0; i < 36; ++i) acc[i] = 0.f;
    #pragma unroll 4
    for (int rw = 0; rw < RWIN; ++rw) {
        int r = rlo + rw;
        float df = dist - r * (10.f / 63.f);
        float rbf = __expf(-df * df * 20.48f);
        const ushort* wp = &s_wq[hg][r][0];
        uint4 wa = *(const uint4*)(wp);        // hs 0..7
        uint4 wb = *(const uint4*)(wp + 8);    // hs 8..15
        uint4 wc = *(const uint4*)(wp + 16);   // hs 16..23
        uint4 wd = *(const uint4*)(wp + 24);   // hs 24..31
        uint2 we = *(const uint2*)(wp + 32);   // hs 32..35
        FMA8(wa, 0)
        FMA8(wb, 8)
        FMA8(wc, 16)
        FMA8(wd, 24)
        acc[32] = fmaf(b2f_lo(we.x), rbf, acc[32]);
        acc[33] = fmaf(b2f_hi(we.x), rbf, acc[33]);
        acc[34] = fmaf(b2f_lo(we.y), rbf, acc[34]);
        acc[35] = fmaf(b2f_hi(we.y), rbf, acc[35]);
    }
    const ushort* sb = sbuf_bf + (((size_t)(b * NH + hg * 4) * NL) + l) * NL + m;
    #pragma unroll
    for (int hh = 0; hh < 4; ++hh) {
        float sc = 0.f;
        #pragma unroll
        for (int s = 0; s < NS; ++s) sc = fmaf(sph[s], acc[hh * NS + s], sc);
        s_l[hg * 4 + hh][m] = sc + b2f(sb[(size_t)hh * NL * NL]);
    }
    __syncthreads();

    int wv = t >> 6, lane = t & 63;
    {
        float v0 = s_l[wv][lane], v1 = s_l[wv][lane + 64];
        float v2 = s_l[wv][lane + 128], v3 = s_l[wv][lane + 192];
        float mx = fmaxf(fmaxf(v0, v1), fmaxf(v2, v3));
        #pragma unroll
        for (int off = 32; off; off >>= 1) mx = fmaxf(mx, __shfl_xor(mx, off, 64));
        float p0 = __expf(v0 - mx), p1 = __expf(v1 - mx);
        float p2 = __expf(v2 - mx), p3 = __expf(v3 - mx);
        float sm = p0 + p1 + p2 + p3;
        #pragma unroll
        for (int off = 32; off; off >>= 1) sm += __shfl_xor(sm, off, 64);
        float inv = 1.f / sm;
        s_l[wv][lane] = p0 * inv;
        s_l[wv][lane + 64] = p1 * inv;
        s_l[wv][lane + 128] = p2 * inv;
        s_l[wv][lane + 192] = p3 * inv;
    }
    __syncthreads();

    // --- PV: thread = (d-quad p, m-quarter q); uint2 = 4 bf16 dims/load ---
    {
        int p = t & 127, q = t >> 7;
        int d0 = p * 4;
        int h0 = p >> 4;                 // = (4p)>>6
        float a0 = 0.f, a1 = 0.f, a2 = 0.f, a3 = 0.f;
        const ushort* vb = src_bf + ((size_t)(b * NL + q * 64)) * ND + d0;
        const float* wl = &s_l[h0][q * 64];
        #pragma unroll 4
        for (int mm = 0; mm < 64; ++mm) {
            float w = wl[mm];
            uint2 u = *(const uint2*)(vb + (size_t)mm * ND);
            a0 = fmaf(w, b2f_lo(u.x), a0);
            a1 = fmaf(w, b2f_hi(u.x), a1);
            a2 = fmaf(w, b2f_lo(u.y), a2);
            a3 = fmaf(w, b2f_hi(u.y), a3);
        }
        *(float4*)&s_pv[q][d0] = make_float4(a0, a1, a2, a3);
    }
    __syncthreads();

    int d = t;
    float av = (s_pv[0][d] + s_pv[1][d]) + (s_pv[2][d] + s_pv[3][d]);
    float x0 = src[(size_t)row * ND + d] + av;
    float mu = block_sum8(x0, s_red) * (1.f / 512.f);
    float e0 = x0 - mu;
    float var = block_sum8(e0 * e0, s_red) * (1.f / 512.f);
    float rs = rsqrtf(var + 1e-5f);
    float o = e0 * rs * gamma1[d] + beta1[d];
    x1buf[(size_t)row * ND + d] = o;
    x1bf[(size_t)row * ND + d] = f2b(o);
}

// ---------------------------------------------------------------------------
// K3 (MFMA): hbf = bf16(leaky_relu(x1bf @ w1t^T + b1))
// ---------------------------------------------------------------------------
__global__ __launch_bounds__(256) void k3_mfma(const ushort* __restrict__ A,
                                               const ushort* __restrict__ Bt,
                                               const float* __restrict__ bias,
                                               ushort* __restrict__ C) {
    const int K = 512, N = 2048;
    int n0 = blockIdx.x * 64, m0 = blockIdx.y * 64;
    int t = threadIdx.x;
    int w = t >> 6, l = t & 63;
    __shared__ ushort As[64][40];
    __shared__ ushort Bs[64][40];
    f32x4 acc0 = {0.f, 0.f, 0.f, 0.f}, acc1 = acc0, acc2 = acc0, acc3 = acc0;
    int sr = t >> 2, sq = (t & 3) * 8;
    const ushort* Ap = A + (size_t)(m0 + sr) * K + sq;
    const ushort* Bp = Bt + (size_t)(n0 + sr) * K + sq;
    int lr = l & 15, lk = (l >> 4) * 8;
    for (int k0 = 0; k0 < K; k0 += 32) {
        uint4 av = *(const uint4*)(Ap + k0);
        uint4 bv = *(const uint4*)(Bp + k0);
        __syncthreads();
        *(uint4*)&As[sr][sq] = av;
        *(uint4*)&Bs[sr][sq] = bv;
        __syncthreads();
        bf16x8 af = *(const bf16x8*)&As[w * 16 + lr][lk];
        bf16x8 b0 = *(const bf16x8*)&Bs[0 * 16 + lr][lk];
        bf16x8 b1v = *(const bf16x8*)&Bs[1 * 16 + lr][lk];
        bf16x8 b2v = *(const bf16x8*)&Bs[2 * 16 + lr][lk];
        bf16x8 b3 = *(const bf16x8*)&Bs[3 * 16 + lr][lk];
        acc0 = __builtin_amdgcn_mfma_f32_16x16x32_bf16(af, b0, acc0, 0, 0, 0);
        acc1 = __builtin_amdgcn_mfma_f32_16x16x32_bf16(af, b1v, acc1, 0, 0, 0);
        acc2 = __builtin_amdgcn_mfma_f32_16x16x32_bf16(af, b2v, acc2, 0, 0, 0);
        acc3 = __builtin_amdgcn_mfma_f32_16x16x32_bf16(af, b3, acc3, 0, 0, 0);
    }
    int rbase = m0 + w * 16 + (l >> 4) * 4;
    #pragma unroll
    for (int e = 0; e < 4; ++e) {
        int row = rbase + e;
        float v;
        int col0 = n0 + lr;
        v = acc0[e] + bias[col0];
        C[(size_t)row * N + col0] = f2b(v >= 0.f ? v : 0.01f * v);
        v = acc1[e] + bias[col0 + 16];
        C[(size_t)row * N + col0 + 16] = f2b(v >= 0.f ? v : 0.01f * v);
        v = acc2[e] + bias[col0 + 32];
        C[(size_t)row * N + col0 + 32] = f2b(v >= 0.f ? v : 0.01f * v);
        v = acc3[e] + bias[col0 + 48];
        C[(size_t)row * N + col0 + 48] = f2b(v >= 0.f ? v : 0.01f * v);
    }
}

// ---------------------------------------------------------------------------
// K4 (MFMA): zpart[ks] = hbf[:, ks*512:+512] @ w2t^T chunk -> fp32
// ---------------------------------------------------------------------------
__global__ __launch_bounds__(256) void k4_mfma(const ushort* __restrict__ A,
                                               const ushort* __restrict__ Bt,
                                               float* __restrict__ Cp) {
    const int K = 2048, N = 512;
    int n0 = blockIdx.x * 64, m0 = blockIdx.y * 64;
    int ks = blockIdx.z;
    int t = threadIdx.x;
    int w = t >> 6, l = t & 63;
    __shared__ ushort As[64][40];
    __shared__ ushort Bs[64][40];
    f32x4 acc0 = {0.f, 0.f, 0.f, 0.f}, acc1 = acc0, acc2 = acc0, acc3 = acc0;
    int sr = t >> 2, sq = (t & 3) * 8;
    const ushort* Ap = A + (size_t)(m0 + sr) * K + ks * 512 + sq;
    const ushort* Bp = Bt + (size_t)(n0 + sr) * K + ks * 512 + sq;
    int lr = l & 15, lk = (l >> 4) * 8;
    for (int k0 = 0; k0 < 512; k0 += 32) {
        uint4 av = *(const uint4*)(Ap + k0);
        uint4 bv = *(const uint4*)(Bp + k0);
        __syncthreads();
        *(uint4*)&As[sr][sq] = av;
        *(uint4*)&Bs[sr][sq] = bv;
        __syncthreads();
        bf16x8 af = *(const bf16x8*)&As[w * 16 + lr][lk];
        bf16x8 b0 = *(const bf16x8*)&Bs[0 * 16 + lr][lk];
        bf16x8 b1v = *(const bf16x8*)&Bs[1 * 16 + lr][lk];
        bf16x8 b2v = *(const bf16x8*)&Bs[2 * 16 + lr][lk];
        bf16x8 b3 = *(const bf16x8*)&Bs[3 * 16 + lr][lk];
        acc0 = __builtin_amdgcn_mfma_f32_16x16x32_bf16(af, b0, acc0, 0, 0, 0);
        acc1 = __builtin_amdgcn_mfma_f32_16x16x32_bf16(af, b1v, acc1, 0, 0, 0);
        acc2 = __builtin_amdgcn_mfma_f32_16x16x32_bf16(af, b2v, acc2, 0, 0, 0);
        acc3 = __builtin_amdgcn_mfma_f32_16x16x32_bf16(af, b3, acc3, 0, 0, 0);
    }
    float* out = Cp + ((size_t)ks << 18);
    int rbase = m0 + w * 16 + (l >> 4) * 4;
    #pragma unroll
    for (int e = 0; e < 4; ++e) {
        int row = rbase + e;
        int col0 = n0 + lr;
        out[(size_t)row * N + col0] = acc0[e];
        out[(size_t)row * N + col0 + 16] = acc1[e];
        out[(size_t)row * N + col0 + 32] = acc2[e];
        out[(size_t)row * N + col0 + 48] = acc3[e];
    }
}

// ---------------------------------------------------------------------------
// K5: z = x1 + b2 + sum_ks zpart[ks]; out = LayerNorm2(z)
// ---------------------------------------------------------------------------
__global__ __launch_bounds__(256) void k5_final(const float* __restrict__ x1buf,
                                                const float* __restrict__ zpart,
                                                const float* __restrict__ b2,
                                                const float* __restrict__ gamma2,
                                                const float* __restrict__ beta2,
                                                float* __restrict__ out) {
    int row = blockIdx.x;
    int t = threadIdx.x;
    int d0 = t * 2;
    __shared__ float s_red[8];
    size_t off = (size_t)row * ND + d0;
    float2 v = *(const float2*)(x1buf + off);
    float2 bb = *(const float2*)(b2 + d0);
    float z0 = v.x + bb.x, z1 = v.y + bb.y;
    #pragma unroll
    for (int ks = 0; ks < 4; ++ks) {
        float2 p = *(const float2*)(zpart + ((size_t)ks << 18) + off);
        z0 += p.x;
        z1 += p.y;
    }
    float mu = block_sum4(z0 + z1, s_red) * (1.f / 512.f);
    float e0 = z0 - mu, e1 = z1 - mu;
    float var = block_sum4(e0 * e0 + e1 * e1, s_red) * (1.f / 512.f);
    float rs = rsqrtf(var + 1e-5f);
    float2 g = *(const float2*)(gamma2 + d0), be = *(const float2*)(beta2 + d0);
    *(float2*)(out + off) = make_float2(e0 * rs * g.x + be.x, e1 * rs * g.y + be.y);
}

// ---------------------------------------------------------------------------
extern "C" void kernel_launch(void* const* d_in, const int* in_sizes, int n_in,
                              void* d_out, int out_size, void* d_ws, size_t ws_size,
                              hipStream_t stream) {
    const float* src      = (const float*)d_in[0];
    const float* rel_diss = (const float*)d_in[1];
    const float* rel_dirs = (const float*)d_in[2];
    const float* rp_w     = (const float*)d_in[3];
    // d_in[4] = rp_b: constant over softmax axis -> cancels exactly; skipped
    const float* w1  = (const float*)d_in[5];
    const float* b1  = (const float*)d_in[6];
    const float* w2  = (const float*)d_in[7];
    const float* b2  = (const float*)d_in[8];
    const float* g1  = (const float*)d_in[9];
    const float* be1 = (const float*)d_in[10];
    const float* g2  = (const float*)d_in[11];
    const float* be2 = (const float*)d_in[12];
    float* out = (float*)d_out;

    float* ws = (float*)d_ws;
    float* x1buf = ws;                            // 262144 f
    float* zpart = x1buf + 262144;                // 1048576 f
    ushort* Wq   = (ushort*)(zpart + 1048576);    // 2359296 u16 (bf16)
    ushort* sbuf_bf = Wq + 2359296;               // 1048576 u16
    ushort* w1t  = sbuf_bf + 1048576;             // 1048576 u16
    ushort* w2t  = w1t + 1048576;                 // 1048576 u16
    ushort* x1bf = w2t + 1048576;                 // 262144 u16
    ushort* hbf  = x1bf + 262144;                 // 1048576 u16
    ushort* src_bf = hbf + 1048576;               // 262144 u16

    k_pre<<<1600, 256, 0, stream>>>(src, rp_w, w1, w2, Wq, sbuf_bf, w1t, w2t, src_bf);
    k2_fused<<<512, 512, 0, stream>>>(src, src_bf, rel_diss, rel_dirs, Wq, sbuf_bf,
                                      g1, be1, x1buf, x1bf);
    k3_mfma<<<dim3(32, 8), 256, 0, stream>>>(x1bf, w1t, b1, hbf);
    k4_mfma<<<dim3(8, 8, 4), 256, 0, stream>>>(hbf, w2t, zpart);
    k5_final<<<512, 256, 0, stream>>>(x1buf, zpart, b2, g2, be2, out);
}